// Round 7
// baseline (1883.032 us; speedup 1.0000x reference)
//
#include <hip/hip_runtime.h>

#define DEV_INLINE __device__ __forceinline__

constexpr int BATCH = 2;
constexpr int HH = 96, WW = 96, CC = 96;
constexpr int DI = 192;
constexpr int NS = 16;
constexpr int LSEQ = HH * WW;        // 9216
constexpr int TT = BATCH * LSEQ;     // 18432
constexpr int NB = 576;              // blocks; block owns 32 tokens
constexpr int CHUNK = 16;
constexpr int NCHUNK = LSEQ / CHUNK; // 576 per batch
constexpr int SUP = 24, NSUP = NCHUNK / SUP; // 24
constexpr int QDN = DI * NS;         // 3072

typedef __attribute__((ext_vector_type(8))) short bf16x8;
typedef __attribute__((ext_vector_type(4))) float f32x4;

DEV_INLINE float silu_f(float x) { return x / (1.f + __expf(-x)); }
DEV_INLINE float softplus_f(float x) {
  return fmaxf(x, 0.f) + log1pf(__expf(-fabsf(x)));
}
DEV_INLINE ushort f2bf(float f) {
  union { float f; unsigned u; } c; c.f = f;
  unsigned u = c.u + 0x7FFF + ((c.u >> 16) & 1);
  return (ushort)(u >> 16);
}
DEV_INLINE float bf2f(ushort u) {
  union { unsigned u; float f; } c; c.u = ((unsigned)u) << 16; return c.f;
}

struct SM {
  ushort xm[32][200];    // u (conv1d+silu), persists P3->P7
  ushort dlt[32][200];   // delta bf16, persists P3->P7; reused as yg in P7
  float  bc[32][36];     // B|C fp32 per token
  union {
    ushort a[32][104];   // P1: LN-staged A tile
    ushort xc[32][200];  // P2: conv2d output
    ushort y[32][200];   // P7: gated scan output
  } t;
};

// device-scope hierarchical barrier: 9 groups of 64 blocks, flag release
DEV_INLINE void gbar(unsigned* bar, int phase) {
  __threadfence();
  __syncthreads();
  if (threadIdx.x == 0) {
    const int g = blockIdx.x >> 6;
    __hip_atomic_fetch_add(&bar[phase * 16 + g], 1u, __ATOMIC_ACQ_REL,
                           __HIP_MEMORY_SCOPE_AGENT);
    if (blockIdx.x == 0) {
      unsigned sum;
      do {
        sum = 0;
        for (int i = 0; i < 9; ++i)
          sum += __hip_atomic_load(&bar[phase * 16 + i], __ATOMIC_ACQUIRE,
                                   __HIP_MEMORY_SCOPE_AGENT);
        if (sum < (unsigned)NB) __builtin_amdgcn_s_sleep(8);
      } while (sum < (unsigned)NB);
      __hip_atomic_store(&bar[phase * 16 + 15], 1u, __ATOMIC_RELEASE,
                         __HIP_MEMORY_SCOPE_AGENT);
    } else {
      while (__hip_atomic_load(&bar[phase * 16 + 15], __ATOMIC_ACQUIRE,
                               __HIP_MEMORY_SCOPE_AGENT) == 0u)
        __builtin_amdgcn_s_sleep(8);
    }
  }
  __syncthreads();
  __threadfence();
}

__global__ __launch_bounds__(256, 3)
void mega_kernel(const float* __restrict__ x, const float* __restrict__ norm_w,
                 const float* __restrict__ norm_b, const float* __restrict__ in_proj_w,
                 const float* __restrict__ conv2d_w, const float* __restrict__ m_in_proj,
                 const float* __restrict__ m_c1d_w, const float* __restrict__ m_c1d_b,
                 const float* __restrict__ m_x_proj, const float* __restrict__ m_dt_w,
                 const float* __restrict__ m_dt_b, const float* __restrict__ m_A_log,
                 const float* __restrict__ m_D, const float* __restrict__ m_out_w,
                 const float* __restrict__ out_w, float* __restrict__ out,
                 unsigned* bar,
                 ushort* __restrict__ Wt0, ushort* __restrict__ Wt1,
                 ushort* __restrict__ Wt2, ushort* __restrict__ Wt3,
                 ushort* __restrict__ Wxt, ushort* __restrict__ Wdtt,
                 float* __restrict__ cw1T, float* __restrict__ cw2T,
                 ushort* __restrict__ xz0, ushort* __restrict__ xz1,
                 float* __restrict__ P, float* __restrict__ E,
                 float* __restrict__ SP, float* __restrict__ SE,
                 float* __restrict__ Hsup, float* __restrict__ Hin)
{
  __shared__ SM sm;
  const int tid = threadIdx.x;
  const int bid = blockIdx.x;
  const int T0 = bid * 32;
  const int wv = tid >> 6, lane = tid & 63;
  const int l16 = lane & 15, quad = lane >> 4;
  const f32x4 z4 = {0.f, 0.f, 0.f, 0.f};

  // ---------- P0: weight cast / transpose / permute ----------
  for (int id = bid * 256 + tid; id < 189696; id += NB * 256) {
    if (id < 36864) {
      int k = id % 96, n = id / 96;
      Wt0[id] = f2bf(in_proj_w[k * 384 + n]);
    } else if (id < 110592) {
      int j = id - 36864; int k = j % 192, n = j / 192;
      Wt1[j] = f2bf(m_in_proj[k * 384 + n]);
    } else if (id < 147456) {
      int j = id - 110592; int k = j % 192, n = j / 192;
      Wt2[j] = f2bf(m_out_w[k * 192 + n]);
    } else if (id < 172032) {
      int j = id - 147456; int k = j % 192, n = j / 192;
      Wt3[j] = (n < 96) ? f2bf(out_w[k * 96 + n]) : (ushort)0;
    } else if (id < 181248) {
      int j = id - 172032; int k = j % 192, n = j / 192;   // Wxt[48][192]
      float v = 0.f;
      if (n < 16) v = m_x_proj[k * 44 + 12 + n];
      else if (n < 32) v = m_x_proj[k * 44 + 28 + (n - 16)];
      else if (n < 44) v = m_x_proj[k * 44 + (n - 32)];
      Wxt[j] = f2bf(v);
    } else if (id < 187392) {
      int j = id - 181248; int r = j % 32, d = j / 32;     // Wdtt[192][32]
      Wdtt[j] = (r < 12) ? f2bf(m_dt_w[r * 192 + d]) : (ushort)0;
    } else if (id < 187968) {
      int j = id - 187392; int k = j / 192, d = j % 192;   // cw1T[3][192]
      cw1T[j] = m_c1d_w[d * 3 + k];
    } else {
      int j = id - 187968; int k = j / 192, d = j % 192;   // cw2T[9][192]
      cw2T[j] = conv2d_w[d * 9 + k];
    }
  }
  gbar(bar, 0);

  // ---------- P1: LayerNorm + in_proj GEMM (K=96, N=384) ----------
  {
    const int tok = tid >> 3, h = tid & 7;   // 8 threads/token, 12 floats each
    const float* xr = x + (size_t)(T0 + tok) * 96 + h * 12;
    float v[12]; float s = 0.f, ss = 0.f;
#pragma unroll
    for (int i = 0; i < 3; ++i) {
      float4 t4 = *(const float4*)(xr + i * 4);
      v[i*4+0] = t4.x; v[i*4+1] = t4.y; v[i*4+2] = t4.z; v[i*4+3] = t4.w;
      s += (t4.x + t4.y) + (t4.z + t4.w);
      ss += (t4.x*t4.x + t4.y*t4.y) + (t4.z*t4.z + t4.w*t4.w);
    }
#pragma unroll
    for (int off = 4; off >= 1; off >>= 1) {
      s += __shfl_xor(s, off);
      ss += __shfl_xor(ss, off);
    }
    float mean = s * (1.f / 96.f);
    float var = ss * (1.f / 96.f) - mean * mean;
    float rstd = rsqrtf(var + 1e-5f);
    const float* wr = norm_w + h * 12;
    const float* br = norm_b + h * 12;
    unsigned* dst = (unsigned*)&sm.t.a[tok][h * 12];
#pragma unroll
    for (int i = 0; i < 3; ++i) {
      float4 w4 = *(const float4*)(wr + i * 4);
      float4 b4 = *(const float4*)(br + i * 4);
      dst[i*2+0] = (unsigned)f2bf((v[i*4+0]-mean)*rstd*w4.x + b4.x)
                 | ((unsigned)f2bf((v[i*4+1]-mean)*rstd*w4.y + b4.y) << 16);
      dst[i*2+1] = (unsigned)f2bf((v[i*4+2]-mean)*rstd*w4.z + b4.z)
                 | ((unsigned)f2bf((v[i*4+3]-mean)*rstd*w4.w + b4.w) << 16);
    }
  }
  __syncthreads();
  {
    const int sh = (wv >> 1) * 16;     // strip
    const int nh = (wv & 1) * 192;     // n-half
    f32x4 acc[12];
#pragma unroll
    for (int j = 0; j < 12; ++j) acc[j] = z4;
#pragma unroll
    for (int k0 = 0; k0 < 96; k0 += 32) {
      bf16x8 af = *(const bf16x8*)&sm.t.a[sh + l16][k0 + quad * 8];
#pragma unroll
      for (int nj = 0; nj < 12; ++nj) {
        bf16x8 wf = *(const bf16x8*)(Wt0 + (size_t)(nh + nj*16 + l16) * 96 + k0 + quad * 8);
        acc[nj] = __builtin_amdgcn_mfma_f32_16x16x32_bf16(wf, af, acc[nj], 0, 0, 0);
      }
    }
    const int token = T0 + sh + l16;
#pragma unroll
    for (int nj = 0; nj < 12; ++nj) {
      const int nb = nh + nj * 16 + quad * 4;
      ushort4 o;
      o.x = f2bf(acc[nj][0]); o.y = f2bf(acc[nj][1]);
      o.z = f2bf(acc[nj][2]); o.w = f2bf(acc[nj][3]);
      *(ushort4*)(xz0 + (size_t)token * 384 + nb) = o;
    }
  }
  gbar(bar, 1);

  // ---------- P2: conv2d 3x3 + SiLU (LDS out) + m_in_proj GEMM ----------
  for (int task = tid; task < 1536; task += 256) {
    int dq = task % 48, tok = task / 48;
    int t = T0 + tok;
    int b = t / LSEQ, r = t % LSEQ;
    int i = r / 96, j = r % 96;
    int d = dq * 4;
    float a0 = 0.f, a1 = 0.f, a2 = 0.f, a3 = 0.f;
#pragma unroll
    for (int ki = 0; ki < 3; ++ki) {
      int ii = i + ki - 1;
      if (ii < 0 || ii >= 96) continue;
#pragma unroll
      for (int kj = 0; kj < 3; ++kj) {
        int jj = j + kj - 1;
        if (jj < 0 || jj >= 96) continue;
        int nt = b * LSEQ + ii * 96 + jj;
        const ushort4 v = *(const ushort4*)(xz0 + (size_t)nt * 384 + d);
        const float4 w4 = *(const float4*)(cw2T + (ki * 3 + kj) * 192 + d);
        a0 = fmaf(bf2f(v.x), w4.x, a0);
        a1 = fmaf(bf2f(v.y), w4.y, a1);
        a2 = fmaf(bf2f(v.z), w4.z, a2);
        a3 = fmaf(bf2f(v.w), w4.w, a3);
      }
    }
    ushort4 o;
    o.x = f2bf(silu_f(a0)); o.y = f2bf(silu_f(a1));
    o.z = f2bf(silu_f(a2)); o.w = f2bf(silu_f(a3));
    *(ushort4*)&sm.t.xc[tok][d] = o;
  }
  __syncthreads();
  {
    const int sh = (wv >> 1) * 16;
    const int nh = (wv & 1) * 192;
    f32x4 acc[12];
#pragma unroll
    for (int j = 0; j < 12; ++j) acc[j] = z4;
#pragma unroll
    for (int k0 = 0; k0 < 192; k0 += 32) {
      bf16x8 af = *(const bf16x8*)&sm.t.xc[sh + l16][k0 + quad * 8];
#pragma unroll
      for (int nj = 0; nj < 12; ++nj) {
        bf16x8 wf = *(const bf16x8*)(Wt1 + (size_t)(nh + nj*16 + l16) * 192 + k0 + quad * 8);
        acc[nj] = __builtin_amdgcn_mfma_f32_16x16x32_bf16(wf, af, acc[nj], 0, 0, 0);
      }
    }
    const int token = T0 + sh + l16;
#pragma unroll
    for (int nj = 0; nj < 12; ++nj) {
      const int nb = nh + nj * 16 + quad * 4;
      ushort4 o;
      o.x = f2bf(acc[nj][0]); o.y = f2bf(acc[nj][1]);
      o.z = f2bf(acc[nj][2]); o.w = f2bf(acc[nj][3]);
      *(ushort4*)(xz1 + (size_t)token * 384 + nb) = o;
    }
  }
  gbar(bar, 2);

  // ---------- P3: conv1d + x_proj + dt_proj + scan phase 1 ----------
  for (int task = tid; task < 1536; task += 256) {
    int dq = task % 48, tok = task / 48;
    int t = T0 + tok, l = t % LSEQ;
    int d = dq * 4;
    float a0 = m_c1d_b[d], a1 = m_c1d_b[d+1], a2 = m_c1d_b[d+2], a3 = m_c1d_b[d+3];
#pragma unroll
    for (int k = 0; k < 3; ++k) {
      if (l + k - 2 < 0) continue;
      const ushort4 v = *(const ushort4*)(xz1 + (size_t)(t + k - 2) * 384 + d);
      const float4 w4 = *(const float4*)(cw1T + k * 192 + d);
      a0 = fmaf(bf2f(v.x), w4.x, a0);
      a1 = fmaf(bf2f(v.y), w4.y, a1);
      a2 = fmaf(bf2f(v.z), w4.z, a2);
      a3 = fmaf(bf2f(v.w), w4.w, a3);
    }
    ushort4 o;
    o.x = f2bf(silu_f(a0)); o.y = f2bf(silu_f(a1));
    o.z = f2bf(silu_f(a2)); o.w = f2bf(silu_f(a3));
    *(ushort4*)&sm.xm[tok][d] = o;
  }
  __syncthreads();
  {
    const int s = wv & 1;          // strip
    const int role = wv >> 1;      // 0: B,C   1: dt + dt_proj
    const int tokb = s * 16;
    if (role == 0) {
      f32x4 aB = z4, aC = z4;
#pragma unroll
      for (int k0 = 0; k0 < 192; k0 += 32) {
        bf16x8 uf = *(const bf16x8*)&sm.xm[tokb + l16][k0 + quad * 8];
        bf16x8 wB = *(const bf16x8*)(Wxt + (size_t)(l16) * 192 + k0 + quad * 8);
        bf16x8 wC = *(const bf16x8*)(Wxt + (size_t)(16 + l16) * 192 + k0 + quad * 8);
        aB = __builtin_amdgcn_mfma_f32_16x16x32_bf16(wB, uf, aB, 0, 0, 0);
        aC = __builtin_amdgcn_mfma_f32_16x16x32_bf16(wC, uf, aC, 0, 0, 0);
      }
      *(float4*)&sm.bc[tokb + l16][quad * 4] = make_float4(aB[0], aB[1], aB[2], aB[3]);
      *(float4*)&sm.bc[tokb + l16][16 + quad * 4] = make_float4(aC[0], aC[1], aC[2], aC[3]);
    } else {
      f32x4 aD = z4;
#pragma unroll
      for (int k0 = 0; k0 < 192; k0 += 32) {
        bf16x8 uf = *(const bf16x8*)&sm.xm[tokb + l16][k0 + quad * 8];
        bf16x8 wD = *(const bf16x8*)(Wxt + (size_t)(32 + l16) * 192 + k0 + quad * 8);
        aD = __builtin_amdgcn_mfma_f32_16x16x32_bf16(wD, uf, aD, 0, 0, 0);
      }
      bf16x8 dtf;
#pragma unroll
      for (int j = 0; j < 8; ++j) {
        int n = quad * 8 + j;
        int src = ((n >> 2) & 3) * 16 + l16;
        float tv = __shfl(aD[j & 3], src);
        dtf[j] = (short)((n < 16) ? f2bf(tv) : (ushort)0);
      }
      f32x4 a2[12];
#pragma unroll
      for (int jj = 0; jj < 12; ++jj) {
        bf16x8 wf = *(const bf16x8*)(Wdtt + (size_t)(jj * 16 + l16) * 32 + quad * 8);
        a2[jj] = __builtin_amdgcn_mfma_f32_16x16x32_bf16(wf, dtf, z4, 0, 0, 0);
      }
#pragma unroll
      for (int jj = 0; jj < 12; ++jj) {
        const int nb = jj * 16 + quad * 4;
        const float4 b4 = *(const float4*)(m_dt_b + nb);
        ushort4 o;
        o.x = f2bf(softplus_f(a2[jj][0] + b4.x));
        o.y = f2bf(softplus_f(a2[jj][1] + b4.y));
        o.z = f2bf(softplus_f(a2[jj][2] + b4.z));
        o.w = f2bf(softplus_f(a2[jj][3] + b4.w));
        *(ushort4*)&sm.dlt[tokb + l16][nb] = o;
      }
    }
  }
  __syncthreads();
  for (int task = tid; task < 384; task += 256) {
    const int d = task % 192, c = task / 192;
    float Av[16];
#pragma unroll
    for (int j = 0; j < 16; ++j) Av[j] = -__expf(m_A_log[d * 16 + j]);
    float e[16];
#pragma unroll
    for (int j = 0; j < 16; ++j) e[j] = 0.f;
    float sdl = 0.f;
    for (int l = 0; l < CHUNK; ++l) {
      const int tl = c * 16 + l;
      float dl = bf2f(sm.dlt[tl][d]);
      float u  = bf2f(sm.xm[tl][d]);
      const float4 B0 = *(const float4*)&sm.bc[tl][0];
      const float4 B1 = *(const float4*)&sm.bc[tl][4];
      const float4 B2 = *(const float4*)&sm.bc[tl][8];
      const float4 B3 = *(const float4*)&sm.bc[tl][12];
      const float Bv[16] = {B0.x, B0.y, B0.z, B0.w, B1.x, B1.y, B1.z, B1.w,
                            B2.x, B2.y, B2.z, B2.w, B3.x, B3.y, B3.z, B3.w};
      float du = dl * u;
      sdl += dl;
#pragma unroll
      for (int j = 0; j < 16; ++j) {
        float a = __expf(dl * Av[j]);
        e[j] = fmaf(a, e[j], du * Bv[j]);
      }
    }
    const int batch = bid / 288;
    const int gci = (bid % 288) * 2 + c;
    size_t base = ((size_t)(batch * NCHUNK + gci)) * QDN + d * 16;
#pragma unroll
    for (int j = 0; j < 16; ++j) {
      P[base + j] = __expf(Av[j] * sdl);
      E[base + j] = e[j];
    }
  }
  gbar(bar, 3);

  // ---------- P4: scan2a (per-super product/accum) ----------
  {
    const int id = bid * 256 + tid;            // 147456 = BATCH*NSUP*QDN
    const int q = id % QDN;
    const int s = (id / QDN) % NSUP;
    const int batch = id / (QDN * NSUP);
    float cp = 1.f, ce = 0.f;
#pragma unroll 4
    for (int c = 0; c < SUP; ++c) {
      size_t idx = ((size_t)(batch * NCHUNK + s * SUP + c)) * QDN + q;
      float p = P[idx], e = E[idx];
      ce = fmaf(p, ce, e);
      cp *= p;
    }
    SP[id] = cp; SE[id] = ce;
  }
  gbar(bar, 4);

  // ---------- P5: scan2b (serial over supers) ----------
  {
    const int id = bid * 256 + tid;
    if (id < BATCH * QDN) {
      const int q = id % QDN, batch = id / QDN;
      float carry = 0.f;
#pragma unroll
      for (int s = 0; s < NSUP; ++s) {
        size_t idx = ((size_t)(batch * NSUP + s)) * QDN + q;
        Hsup[idx] = carry;
        carry = fmaf(SP[idx], carry, SE[idx]);
      }
    }
  }
  gbar(bar, 5);

  // ---------- P6: scan2c (expand to per-chunk inbound) ----------
  {
    const int id = bid * 256 + tid;
    const int q = id % QDN;
    const int s = (id / QDN) % NSUP;
    const int batch = id / (QDN * NSUP);
    float h = Hsup[id];
#pragma unroll 4
    for (int c = 0; c < SUP; ++c) {
      size_t idx = ((size_t)(batch * NCHUNK + s * SUP + c)) * QDN + q;
      Hin[idx] = h;
      h = fmaf(P[idx], h, E[idx]);
    }
  }
  gbar(bar, 6);

  // ---------- P7: scan3 replay (+gate) + m_out_proj + out_proj ----------
  for (int task = tid; task < 384; task += 256) {
    const int d = task % 192, c = task / 192;
    float Av[16];
#pragma unroll
    for (int j = 0; j < 16; ++j) Av[j] = -__expf(m_A_log[d * 16 + j]);
    const float Dd = m_D[d];
    const int batch = bid / 288;
    const int gci = (bid % 288) * 2 + c;
    size_t base = ((size_t)(batch * NCHUNK + gci)) * QDN + d * 16;
    float h[16];
#pragma unroll
    for (int j = 0; j < 16; ++j) h[j] = Hin[base + j];
    for (int l = 0; l < CHUNK; ++l) {
      const int tl = c * 16 + l;
      const int t = T0 + tl;
      float dl = bf2f(sm.dlt[tl][d]);
      float u  = bf2f(sm.xm[tl][d]);
      const float4 B0 = *(const float4*)&sm.bc[tl][0];
      const float4 B1 = *(const float4*)&sm.bc[tl][4];
      const float4 B2 = *(const float4*)&sm.bc[tl][8];
      const float4 B3 = *(const float4*)&sm.bc[tl][12];
      const float4 C0 = *(const float4*)&sm.bc[tl][16];
      const float4 C1 = *(const float4*)&sm.bc[tl][20];
      const float4 C2 = *(const float4*)&sm.bc[tl][24];
      const float4 C3 = *(const float4*)&sm.bc[tl][28];
      const float Bv[16] = {B0.x, B0.y, B0.z, B0.w, B1.x, B1.y, B1.z, B1.w,
                            B2.x, B2.y, B2.z, B2.w, B3.x, B3.y, B3.z, B3.w};
      const float Cv[16] = {C0.x, C0.y, C0.z, C0.w, C1.x, C1.y, C1.z, C1.w,
                            C2.x, C2.y, C2.z, C2.w, C3.x, C3.y, C3.z, C3.w};
      float du = dl * u;
      float y0 = 0.f, y1 = 0.f, y2 = 0.f, y3 = 0.f;
#pragma unroll
      for (int j = 0; j < 16; ++j) {
        float a = __expf(dl * Av[j]);
        h[j] = fmaf(a, h[j], du * Bv[j]);
        if ((j & 3) == 0) y0 = fmaf(h[j], Cv[j], y0);
        else if ((j & 3) == 1) y1 = fmaf(h[j], Cv[j], y1);
        else if ((j & 3) == 2) y2 = fmaf(h[j], Cv[j], y2);
        else y3 = fmaf(h[j], Cv[j], y3);
      }
      float y = (y0 + y1) + (y2 + y3) + u * Dd;
      float z = bf2f(xz1[(size_t)t * 384 + 192 + d]);
      sm.t.y[tl][d] = f2bf(y * silu_f(z));
    }
  }
  __syncthreads();
  {
    // GEMM1 (m_out_proj, N=192) + silu(xz0 gate) -> sm.dlt as yg
    const int s = wv >> 1;
    const int nh = (wv & 1) * 96;
    f32x4 g1[6];
#pragma unroll
    for (int j = 0; j < 6; ++j) g1[j] = z4;
#pragma unroll
    for (int k0 = 0; k0 < 192; k0 += 32) {
      bf16x8 af = *(const bf16x8*)&sm.t.y[s * 16 + l16][k0 + quad * 8];
#pragma unroll
      for (int nj = 0; nj < 6; ++nj) {
        bf16x8 wf = *(const bf16x8*)(Wt2 + (size_t)(nh + nj*16 + l16) * 192 + k0 + quad * 8);
        g1[nj] = __builtin_amdgcn_mfma_f32_16x16x32_bf16(wf, af, g1[nj], 0, 0, 0);
      }
    }
    const int tok = s * 16 + l16;
    const int token = T0 + tok;
#pragma unroll
    for (int nj = 0; nj < 6; ++nj) {
      const int nb = nh + nj * 16 + quad * 4;
      const ushort4 g4 = *(const ushort4*)(xz0 + (size_t)token * 384 + 192 + nb);
      ushort4 o;
      o.x = f2bf(g1[nj][0] * silu_f(bf2f(g4.x)));
      o.y = f2bf(g1[nj][1] * silu_f(bf2f(g4.y)));
      o.z = f2bf(g1[nj][2] * silu_f(bf2f(g4.z)));
      o.w = f2bf(g1[nj][3] * silu_f(bf2f(g4.w)));
      *(ushort4*)&sm.dlt[tok][nb] = o;
    }
  }
  __syncthreads();
  {
    // GEMM2 (out_proj, N=96) + residual -> out fp32
    const int s = wv >> 1;
    const int nh = (wv & 1) * 48;
    f32x4 g2[3];
#pragma unroll
    for (int j = 0; j < 3; ++j) g2[j] = z4;
#pragma unroll
    for (int k0 = 0; k0 < 192; k0 += 32) {
      bf16x8 af = *(const bf16x8*)&sm.dlt[s * 16 + l16][k0 + quad * 8];
#pragma unroll
      for (int nj = 0; nj < 3; ++nj) {
        bf16x8 wf = *(const bf16x8*)(Wt3 + (size_t)(nh + nj*16 + l16) * 192 + k0 + quad * 8);
        g2[nj] = __builtin_amdgcn_mfma_f32_16x16x32_bf16(wf, af, g2[nj], 0, 0, 0);
      }
    }
    const int token = T0 + s * 16 + l16;
#pragma unroll
    for (int nj = 0; nj < 3; ++nj) {
      const int nb = nh + nj * 16 + quad * 4;
      const float4 r4 = *(const float4*)(x + (size_t)token * 96 + nb);
      *(float4*)(out + (size_t)token * 96 + nb) =
          make_float4(g2[nj][0] + r4.x, g2[nj][1] + r4.y,
                      g2[nj][2] + r4.z, g2[nj][3] + r4.w);
    }
  }
}

// ---------------- launch ----------------
extern "C" void kernel_launch(void* const* d_in, const int* in_sizes, int n_in,
                              void* d_out, int out_size, void* d_ws, size_t ws_size,
                              hipStream_t stream)
{
  const float* x         = (const float*)d_in[0];
  const float* norm_w    = (const float*)d_in[1];
  const float* norm_b    = (const float*)d_in[2];
  const float* in_proj_w = (const float*)d_in[3];
  const float* conv2d_w  = (const float*)d_in[4];
  const float* m_in_proj = (const float*)d_in[5];
  const float* m_c1d_w   = (const float*)d_in[6];
  const float* m_c1d_b   = (const float*)d_in[7];
  const float* m_x_proj  = (const float*)d_in[8];
  const float* m_dt_w    = (const float*)d_in[9];
  const float* m_dt_b    = (const float*)d_in[10];
  const float* m_A_log   = (const float*)d_in[11];
  const float* m_D       = (const float*)d_in[12];
  const float* m_out_w   = (const float*)d_in[13];
  const float* out_w     = (const float*)d_in[14];
  float* out = (float*)d_out;

  char* wp = (char*)d_ws;
  auto alloc = [&](size_t bytes) {
    char* r = wp; wp += (bytes + 255) & ~(size_t)255; return r;
  };
  unsigned* bar  = (unsigned*)alloc(512);
  ushort* Wt0    = (ushort*)alloc(36864 * 2);
  ushort* Wt1    = (ushort*)alloc(73728 * 2);
  ushort* Wt2    = (ushort*)alloc(36864 * 2);
  ushort* Wt3    = (ushort*)alloc(24576 * 2);
  ushort* Wxt    = (ushort*)alloc(9216 * 2);
  ushort* Wdtt   = (ushort*)alloc(6144 * 2);
  float*  cw1T   = (float*)alloc(576 * 4);
  float*  cw2T   = (float*)alloc(1728 * 4);
  ushort* xz0    = (ushort*)alloc((size_t)TT * 384 * 2);
  ushort* xz1    = (ushort*)alloc((size_t)TT * 384 * 2);
  float*  P      = (float*)alloc((size_t)BATCH * NCHUNK * QDN * 4);
  float*  E      = (float*)alloc((size_t)BATCH * NCHUNK * QDN * 4);
  float*  SP     = (float*)alloc((size_t)BATCH * NSUP * QDN * 4);
  float*  SE     = (float*)alloc((size_t)BATCH * NSUP * QDN * 4);
  float*  Hsup   = (float*)alloc((size_t)BATCH * NSUP * QDN * 4);
  float*  Hin    = (float*)alloc((size_t)BATCH * NCHUNK * QDN * 4);

  hipMemsetAsync(bar, 0, 512, stream);
  mega_kernel<<<NB, 256, 0, stream>>>(
      x, norm_w, norm_b, in_proj_w, conv2d_w, m_in_proj, m_c1d_w, m_c1d_b,
      m_x_proj, m_dt_w, m_dt_b, m_A_log, m_D, m_out_w, out_w, out,
      bar, Wt0, Wt1, Wt2, Wt3, Wxt, Wdtt, cw1T, cw2T,
      xz0, xz1, P, E, SP, SE, Hsup, Hin);
}

// Round 8
// 1748.386 us; speedup vs baseline: 1.0770x; 1.0770x over previous
//
#include <hip/hip_runtime.h>

#define DEV_INLINE __device__ __forceinline__

constexpr int BATCH = 2;
constexpr int HH = 96, WW = 96, CC = 96;
constexpr int DI = 192;
constexpr int NS = 16;
constexpr int LSEQ = HH * WW;        // 9216
constexpr int TT = BATCH * LSEQ;     // 18432
constexpr int NB = 576;              // blocks; block owns 32 tokens
constexpr int NGRP = 9;              // 576 / 64 barrier groups
constexpr int CHUNK = 16;
constexpr int NCHUNK = LSEQ / CHUNK; // 576 per batch
constexpr int SUP = 24, NSUP = NCHUNK / SUP; // 24
constexpr int QDN = DI * NS;         // 3072

typedef __attribute__((ext_vector_type(8))) short bf16x8;
typedef __attribute__((ext_vector_type(4))) float f32x4;

DEV_INLINE float silu_f(float x) { return x / (1.f + __expf(-x)); }
DEV_INLINE float softplus_f(float x) {
  return fmaxf(x, 0.f) + log1pf(__expf(-fabsf(x)));
}
DEV_INLINE ushort f2bf(float f) {
  union { float f; unsigned u; } c; c.f = f;
  unsigned u = c.u + 0x7FFF + ((c.u >> 16) & 1);
  return (ushort)(u >> 16);
}
DEV_INLINE float bf2f(ushort u) {
  union { unsigned u; float f; } c; c.u = ((unsigned)u) << 16; return c.f;
}

struct SM {
  ushort xm[32][204];    // u (conv1d+silu); stride 204 -> 2-way banks (free)
  ushort dlt[32][204];   // delta bf16; reused as yg in P7
  float  bc[32][36];     // B|C fp32 per token
  union {
    ushort a[32][108];   // P1: LN-staged A tile
    ushort xc[32][204];  // P2: conv2d output
    ushort y[32][204];   // P7: gated scan output
  } t;
};

// low-contention device barrier:
//  - 9 per-group arrival counters, 128B apart
//  - last arriver of a group promotes the top counter
//  - block 0 spins on top (s_sleep backoff), then sets 9 per-group release flags
//  - each block spins only on its group's flag (<=64 pollers/line, backoff)
DEV_INLINE void gbar(unsigned* bar, int phase) {
  __threadfence();
  __syncthreads();
  if (threadIdx.x == 0) {
    unsigned* base = bar + phase * 1024;
    const int g = blockIdx.x >> 6;
    unsigned old = __hip_atomic_fetch_add(&base[g * 32], 1u, __ATOMIC_ACQ_REL,
                                          __HIP_MEMORY_SCOPE_AGENT);
    if (old == 63u)
      __hip_atomic_fetch_add(&base[NGRP * 32], 1u, __ATOMIC_ACQ_REL,
                             __HIP_MEMORY_SCOPE_AGENT);
    if (blockIdx.x == 0) {
      while (__hip_atomic_load(&base[NGRP * 32], __ATOMIC_ACQUIRE,
                               __HIP_MEMORY_SCOPE_AGENT) < (unsigned)NGRP)
        __builtin_amdgcn_s_sleep(16);
      for (int i = 0; i < NGRP; ++i)
        __hip_atomic_store(&base[512 + i * 32], 1u, __ATOMIC_RELEASE,
                           __HIP_MEMORY_SCOPE_AGENT);
    }
    while (__hip_atomic_load(&base[512 + g * 32], __ATOMIC_ACQUIRE,
                             __HIP_MEMORY_SCOPE_AGENT) == 0u)
      __builtin_amdgcn_s_sleep(16);
  }
  __syncthreads();
  __threadfence();
}

__global__ __launch_bounds__(256, 3)
void mega_kernel(const float* __restrict__ x, const float* __restrict__ norm_w,
                 const float* __restrict__ norm_b, const float* __restrict__ in_proj_w,
                 const float* __restrict__ conv2d_w, const float* __restrict__ m_in_proj,
                 const float* __restrict__ m_c1d_w, const float* __restrict__ m_c1d_b,
                 const float* __restrict__ m_x_proj, const float* __restrict__ m_dt_w,
                 const float* __restrict__ m_dt_b, const float* __restrict__ m_A_log,
                 const float* __restrict__ m_D, const float* __restrict__ m_out_w,
                 const float* __restrict__ out_w, float* __restrict__ out,
                 unsigned* bar,
                 ushort* __restrict__ Wt0, ushort* __restrict__ Wt1,
                 ushort* __restrict__ Wt2, ushort* __restrict__ Wt3,
                 ushort* __restrict__ Wxt, ushort* __restrict__ Wdtt,
                 float* __restrict__ cw1T, float* __restrict__ cw2T,
                 ushort* __restrict__ xz0, ushort* __restrict__ xz1,
                 float* __restrict__ P, float* __restrict__ E,
                 float* __restrict__ SP, float* __restrict__ SE,
                 float* __restrict__ Hsup, float* __restrict__ Hin)
{
  __shared__ SM sm;
  const int tid = threadIdx.x;
  const int bid = blockIdx.x;
  const int T0 = bid * 32;
  const int wv = tid >> 6, lane = tid & 63;
  const int l16 = lane & 15, quad = lane >> 4;
  const f32x4 z4 = {0.f, 0.f, 0.f, 0.f};

  // ---------- P0: weight cast / transpose / permute ----------
  for (int id = bid * 256 + tid; id < 189696; id += NB * 256) {
    if (id < 36864) {
      int k = id % 96, n = id / 96;
      Wt0[id] = f2bf(in_proj_w[k * 384 + n]);
    } else if (id < 110592) {
      int j = id - 36864; int k = j % 192, n = j / 192;
      Wt1[j] = f2bf(m_in_proj[k * 384 + n]);
    } else if (id < 147456) {
      int j = id - 110592; int k = j % 192, n = j / 192;
      Wt2[j] = f2bf(m_out_w[k * 192 + n]);
    } else if (id < 172032) {
      int j = id - 147456; int k = j % 192, n = j / 192;
      Wt3[j] = (n < 96) ? f2bf(out_w[k * 96 + n]) : (ushort)0;
    } else if (id < 181248) {
      int j = id - 172032; int k = j % 192, n = j / 192;   // Wxt[48][192]
      float v = 0.f;
      if (n < 16) v = m_x_proj[k * 44 + 12 + n];
      else if (n < 32) v = m_x_proj[k * 44 + 28 + (n - 16)];
      else if (n < 44) v = m_x_proj[k * 44 + (n - 32)];
      Wxt[j] = f2bf(v);
    } else if (id < 187392) {
      int j = id - 181248; int r = j % 32, d = j / 32;     // Wdtt[192][32]
      Wdtt[j] = (r < 12) ? f2bf(m_dt_w[r * 192 + d]) : (ushort)0;
    } else if (id < 187968) {
      int j = id - 187392; int k = j / 192, d = j % 192;   // cw1T[3][192]
      cw1T[j] = m_c1d_w[d * 3 + k];
    } else {
      int j = id - 187968; int k = j / 192, d = j % 192;   // cw2T[9][192]
      cw2T[j] = conv2d_w[d * 9 + k];
    }
  }
  gbar(bar, 0);

  // ---------- P1: LayerNorm + in_proj GEMM (K=96, N=384) ----------
  {
    const int tok = tid >> 3, h = tid & 7;   // 8 threads/token
    const float* xr = x + (size_t)(T0 + tok) * 96 + h * 12;
    float v[12]; float s = 0.f, ss = 0.f;
#pragma unroll
    for (int i = 0; i < 3; ++i) {
      float4 t4 = *(const float4*)(xr + i * 4);
      v[i*4+0] = t4.x; v[i*4+1] = t4.y; v[i*4+2] = t4.z; v[i*4+3] = t4.w;
      s += (t4.x + t4.y) + (t4.z + t4.w);
      ss += (t4.x*t4.x + t4.y*t4.y) + (t4.z*t4.z + t4.w*t4.w);
    }
#pragma unroll
    for (int off = 4; off >= 1; off >>= 1) {
      s += __shfl_xor(s, off);
      ss += __shfl_xor(ss, off);
    }
    float mean = s * (1.f / 96.f);
    float var = ss * (1.f / 96.f) - mean * mean;
    float rstd = rsqrtf(var + 1e-5f);
    const float* wr = norm_w + h * 12;
    const float* br = norm_b + h * 12;
    unsigned* dst = (unsigned*)&sm.t.a[tok][h * 12];
#pragma unroll
    for (int i = 0; i < 3; ++i) {
      float4 w4 = *(const float4*)(wr + i * 4);
      float4 b4 = *(const float4*)(br + i * 4);
      dst[i*2+0] = (unsigned)f2bf((v[i*4+0]-mean)*rstd*w4.x + b4.x)
                 | ((unsigned)f2bf((v[i*4+1]-mean)*rstd*w4.y + b4.y) << 16);
      dst[i*2+1] = (unsigned)f2bf((v[i*4+2]-mean)*rstd*w4.z + b4.z)
                 | ((unsigned)f2bf((v[i*4+3]-mean)*rstd*w4.w + b4.w) << 16);
    }
  }
  __syncthreads();
  {
    const int sh = (wv >> 1) * 16;     // strip
    const int nh = (wv & 1) * 192;     // n-half
    f32x4 acc[12];
#pragma unroll
    for (int j = 0; j < 12; ++j) acc[j] = z4;
#pragma unroll
    for (int k0 = 0; k0 < 96; k0 += 32) {
      bf16x8 af = *(const bf16x8*)&sm.t.a[sh + l16][k0 + quad * 8];
#pragma unroll
      for (int nj = 0; nj < 12; ++nj) {
        bf16x8 wf = *(const bf16x8*)(Wt0 + (size_t)(nh + nj*16 + l16) * 96 + k0 + quad * 8);
        acc[nj] = __builtin_amdgcn_mfma_f32_16x16x32_bf16(wf, af, acc[nj], 0, 0, 0);
      }
    }
    const int token = T0 + sh + l16;
#pragma unroll
    for (int nj = 0; nj < 12; ++nj) {
      const int nb = nh + nj * 16 + quad * 4;
      ushort4 o;
      o.x = f2bf(acc[nj][0]); o.y = f2bf(acc[nj][1]);
      o.z = f2bf(acc[nj][2]); o.w = f2bf(acc[nj][3]);
      *(ushort4*)(xz0 + (size_t)token * 384 + nb) = o;
    }
  }
  gbar(bar, 1);

  // ---------- P2: conv2d 3x3 + SiLU (LDS out) + m_in_proj GEMM ----------
  for (int task = tid; task < 1536; task += 256) {
    int dq = task % 48, tok = task / 48;
    int t = T0 + tok;
    int b = t / LSEQ, r = t % LSEQ;
    int i = r / 96, j = r % 96;
    int d = dq * 4;
    float a0 = 0.f, a1 = 0.f, a2 = 0.f, a3 = 0.f;
#pragma unroll
    for (int ki = 0; ki < 3; ++ki) {
      int ii = i + ki - 1;
      if (ii < 0 || ii >= 96) continue;
#pragma unroll
      for (int kj = 0; kj < 3; ++kj) {
        int jj = j + kj - 1;
        if (jj < 0 || jj >= 96) continue;
        int nt = b * LSEQ + ii * 96 + jj;
        const ushort4 v = *(const ushort4*)(xz0 + (size_t)nt * 384 + d);
        const float4 w4 = *(const float4*)(cw2T + (ki * 3 + kj) * 192 + d);
        a0 = fmaf(bf2f(v.x), w4.x, a0);
        a1 = fmaf(bf2f(v.y), w4.y, a1);
        a2 = fmaf(bf2f(v.z), w4.z, a2);
        a3 = fmaf(bf2f(v.w), w4.w, a3);
      }
    }
    ushort4 o;
    o.x = f2bf(silu_f(a0)); o.y = f2bf(silu_f(a1));
    o.z = f2bf(silu_f(a2)); o.w = f2bf(silu_f(a3));
    *(ushort4*)&sm.t.xc[tok][d] = o;
  }
  __syncthreads();
  {
    const int sh = (wv >> 1) * 16;
    const int nh = (wv & 1) * 192;
    f32x4 acc[12];
#pragma unroll
    for (int j = 0; j < 12; ++j) acc[j] = z4;
#pragma unroll
    for (int k0 = 0; k0 < 192; k0 += 32) {
      bf16x8 af = *(const bf16x8*)&sm.t.xc[sh + l16][k0 + quad * 8];
#pragma unroll
      for (int nj = 0; nj < 12; ++nj) {
        bf16x8 wf = *(const bf16x8*)(Wt1 + (size_t)(nh + nj*16 + l16) * 192 + k0 + quad * 8);
        acc[nj] = __builtin_amdgcn_mfma_f32_16x16x32_bf16(wf, af, acc[nj], 0, 0, 0);
      }
    }
    const int token = T0 + sh + l16;
#pragma unroll
    for (int nj = 0; nj < 12; ++nj) {
      const int nb = nh + nj * 16 + quad * 4;
      ushort4 o;
      o.x = f2bf(acc[nj][0]); o.y = f2bf(acc[nj][1]);
      o.z = f2bf(acc[nj][2]); o.w = f2bf(acc[nj][3]);
      *(ushort4*)(xz1 + (size_t)token * 384 + nb) = o;
    }
  }
  gbar(bar, 2);

  // ---------- P3: conv1d + x_proj + dt_proj + scan phase 1 ----------
  for (int task = tid; task < 1536; task += 256) {
    int dq = task % 48, tok = task / 48;
    int t = T0 + tok, l = t % LSEQ;
    int d = dq * 4;
    float a0 = m_c1d_b[d], a1 = m_c1d_b[d+1], a2 = m_c1d_b[d+2], a3 = m_c1d_b[d+3];
#pragma unroll
    for (int k = 0; k < 3; ++k) {
      if (l + k - 2 < 0) continue;
      const ushort4 v = *(const ushort4*)(xz1 + (size_t)(t + k - 2) * 384 + d);
      const float4 w4 = *(const float4*)(cw1T + k * 192 + d);
      a0 = fmaf(bf2f(v.x), w4.x, a0);
      a1 = fmaf(bf2f(v.y), w4.y, a1);
      a2 = fmaf(bf2f(v.z), w4.z, a2);
      a3 = fmaf(bf2f(v.w), w4.w, a3);
    }
    ushort4 o;
    o.x = f2bf(silu_f(a0)); o.y = f2bf(silu_f(a1));
    o.z = f2bf(silu_f(a2)); o.w = f2bf(silu_f(a3));
    *(ushort4*)&sm.xm[tok][d] = o;
  }
  __syncthreads();
  {
    const int s = wv & 1;          // strip
    const int role = wv >> 1;      // 0: B,C   1: dt + dt_proj
    const int tokb = s * 16;
    if (role == 0) {
      f32x4 aB = z4, aC = z4;
#pragma unroll
      for (int k0 = 0; k0 < 192; k0 += 32) {
        bf16x8 uf = *(const bf16x8*)&sm.xm[tokb + l16][k0 + quad * 8];
        bf16x8 wB = *(const bf16x8*)(Wxt + (size_t)(l16) * 192 + k0 + quad * 8);
        bf16x8 wC = *(const bf16x8*)(Wxt + (size_t)(16 + l16) * 192 + k0 + quad * 8);
        aB = __builtin_amdgcn_mfma_f32_16x16x32_bf16(wB, uf, aB, 0, 0, 0);
        aC = __builtin_amdgcn_mfma_f32_16x16x32_bf16(wC, uf, aC, 0, 0, 0);
      }
      *(float4*)&sm.bc[tokb + l16][quad * 4] = make_float4(aB[0], aB[1], aB[2], aB[3]);
      *(float4*)&sm.bc[tokb + l16][16 + quad * 4] = make_float4(aC[0], aC[1], aC[2], aC[3]);
    } else {
      f32x4 aD = z4;
#pragma unroll
      for (int k0 = 0; k0 < 192; k0 += 32) {
        bf16x8 uf = *(const bf16x8*)&sm.xm[tokb + l16][k0 + quad * 8];
        bf16x8 wD = *(const bf16x8*)(Wxt + (size_t)(32 + l16) * 192 + k0 + quad * 8);
        aD = __builtin_amdgcn_mfma_f32_16x16x32_bf16(wD, uf, aD, 0, 0, 0);
      }
      bf16x8 dtf;
#pragma unroll
      for (int j = 0; j < 8; ++j) {
        int n = quad * 8 + j;
        int src = ((n >> 2) & 3) * 16 + l16;
        float tv = __shfl(aD[j & 3], src);
        dtf[j] = (short)((n < 16) ? f2bf(tv) : (ushort)0);
      }
      f32x4 a2[12];
#pragma unroll
      for (int jj = 0; jj < 12; ++jj) {
        bf16x8 wf = *(const bf16x8*)(Wdtt + (size_t)(jj * 16 + l16) * 32 + quad * 8);
        a2[jj] = __builtin_amdgcn_mfma_f32_16x16x32_bf16(wf, dtf, z4, 0, 0, 0);
      }
#pragma unroll
      for (int jj = 0; jj < 12; ++jj) {
        const int nb = jj * 16 + quad * 4;
        const float4 b4 = *(const float4*)(m_dt_b + nb);
        ushort4 o;
        o.x = f2bf(softplus_f(a2[jj][0] + b4.x));
        o.y = f2bf(softplus_f(a2[jj][1] + b4.y));
        o.z = f2bf(softplus_f(a2[jj][2] + b4.z));
        o.w = f2bf(softplus_f(a2[jj][3] + b4.w));
        *(ushort4*)&sm.dlt[tokb + l16][nb] = o;
      }
    }
  }
  __syncthreads();
  for (int task = tid; task < 384; task += 256) {
    const int d = task % 192, c = task / 192;
    float Av[16];
#pragma unroll
    for (int j = 0; j < 16; ++j) Av[j] = -__expf(m_A_log[d * 16 + j]);
    float e[16];
#pragma unroll
    for (int j = 0; j < 16; ++j) e[j] = 0.f;
    float sdl = 0.f;
    for (int l = 0; l < CHUNK; ++l) {
      const int tl = c * 16 + l;
      float dl = bf2f(sm.dlt[tl][d]);
      float u  = bf2f(sm.xm[tl][d]);
      const float4 B0 = *(const float4*)&sm.bc[tl][0];
      const float4 B1 = *(const float4*)&sm.bc[tl][4];
      const float4 B2 = *(const float4*)&sm.bc[tl][8];
      const float4 B3 = *(const float4*)&sm.bc[tl][12];
      const float Bv[16] = {B0.x, B0.y, B0.z, B0.w, B1.x, B1.y, B1.z, B1.w,
                            B2.x, B2.y, B2.z, B2.w, B3.x, B3.y, B3.z, B3.w};
      float du = dl * u;
      sdl += dl;
#pragma unroll
      for (int j = 0; j < 16; ++j) {
        float a = __expf(dl * Av[j]);
        e[j] = fmaf(a, e[j], du * Bv[j]);
      }
    }
    const int batch = bid / 288;
    const int gci = (bid % 288) * 2 + c;
    size_t base = ((size_t)(batch * NCHUNK + gci)) * QDN + d * 16;
#pragma unroll
    for (int j = 0; j < 16; ++j) {
      P[base + j] = __expf(Av[j] * sdl);
      E[base + j] = e[j];
    }
  }
  gbar(bar, 3);

  // ---------- P4: scan2a (per-super product/accum) ----------
  {
    const int id = bid * 256 + tid;            // 147456 = BATCH*NSUP*QDN
    const int q = id % QDN;
    const int s = (id / QDN) % NSUP;
    const int batch = id / (QDN * NSUP);
    float cp = 1.f, ce = 0.f;
#pragma unroll 4
    for (int c = 0; c < SUP; ++c) {
      size_t idx = ((size_t)(batch * NCHUNK + s * SUP + c)) * QDN + q;
      float p = P[idx], e = E[idx];
      ce = fmaf(p, ce, e);
      cp *= p;
    }
    SP[id] = cp; SE[id] = ce;
  }
  gbar(bar, 4);

  // ---------- P5: scan2b (serial over supers) ----------
  {
    const int id = bid * 256 + tid;
    if (id < BATCH * QDN) {
      const int q = id % QDN, batch = id / QDN;
      float carry = 0.f;
#pragma unroll
      for (int s = 0; s < NSUP; ++s) {
        size_t idx = ((size_t)(batch * NSUP + s)) * QDN + q;
        Hsup[idx] = carry;
        carry = fmaf(SP[idx], carry, SE[idx]);
      }
    }
  }
  gbar(bar, 5);

  // ---------- P6: scan2c (expand to per-chunk inbound) ----------
  {
    const int id = bid * 256 + tid;
    const int q = id % QDN;
    const int s = (id / QDN) % NSUP;
    const int batch = id / (QDN * NSUP);
    float h = Hsup[id];
#pragma unroll 4
    for (int c = 0; c < SUP; ++c) {
      size_t idx = ((size_t)(batch * NCHUNK + s * SUP + c)) * QDN + q;
      Hin[idx] = h;
      h = fmaf(P[idx], h, E[idx]);
    }
  }
  gbar(bar, 6);

  // ---------- P7: scan3 replay (+gate) + m_out_proj + out_proj ----------
  for (int task = tid; task < 384; task += 256) {
    const int d = task % 192, c = task / 192;
    float Av[16];
#pragma unroll
    for (int j = 0; j < 16; ++j) Av[j] = -__expf(m_A_log[d * 16 + j]);
    const float Dd = m_D[d];
    const int batch = bid / 288;
    const int gci = (bid % 288) * 2 + c;
    size_t base = ((size_t)(batch * NCHUNK + gci)) * QDN + d * 16;
    float h[16];
#pragma unroll
    for (int j = 0; j < 16; ++j) h[j] = Hin[base + j];
    for (int l = 0; l < CHUNK; ++l) {
      const int tl = c * 16 + l;
      const int t = T0 + tl;
      float dl = bf2f(sm.dlt[tl][d]);
      float u  = bf2f(sm.xm[tl][d]);
      const float4 B0 = *(const float4*)&sm.bc[tl][0];
      const float4 B1 = *(const float4*)&sm.bc[tl][4];
      const float4 B2 = *(const float4*)&sm.bc[tl][8];
      const float4 B3 = *(const float4*)&sm.bc[tl][12];
      const float4 C0 = *(const float4*)&sm.bc[tl][16];
      const float4 C1 = *(const float4*)&sm.bc[tl][20];
      const float4 C2 = *(const float4*)&sm.bc[tl][24];
      const float4 C3 = *(const float4*)&sm.bc[tl][28];
      const float Bv[16] = {B0.x, B0.y, B0.z, B0.w, B1.x, B1.y, B1.z, B1.w,
                            B2.x, B2.y, B2.z, B2.w, B3.x, B3.y, B3.z, B3.w};
      const float Cv[16] = {C0.x, C0.y, C0.z, C0.w, C1.x, C1.y, C1.z, C1.w,
                            C2.x, C2.y, C2.z, C2.w, C3.x, C3.y, C3.z, C3.w};
      float du = dl * u;
      float y0 = 0.f, y1 = 0.f, y2 = 0.f, y3 = 0.f;
#pragma unroll
      for (int j = 0; j < 16; ++j) {
        float a = __expf(dl * Av[j]);
        h[j] = fmaf(a, h[j], du * Bv[j]);
        if ((j & 3) == 0) y0 = fmaf(h[j], Cv[j], y0);
        else if ((j & 3) == 1) y1 = fmaf(h[j], Cv[j], y1);
        else if ((j & 3) == 2) y2 = fmaf(h[j], Cv[j], y2);
        else y3 = fmaf(h[j], Cv[j], y3);
      }
      float y = (y0 + y1) + (y2 + y3) + u * Dd;
      float z = bf2f(xz1[(size_t)t * 384 + 192 + d]);
      sm.t.y[tl][d] = f2bf(y * silu_f(z));
    }
  }
  __syncthreads();
  {
    // GEMM1 (m_out_proj, N=192) + silu(xz0 gate) -> sm.dlt as yg
    const int s = wv >> 1;
    const int nh = (wv & 1) * 96;
    f32x4 g1[6];
#pragma unroll
    for (int j = 0; j < 6; ++j) g1[j] = z4;
#pragma unroll
    for (int k0 = 0; k0 < 192; k0 += 32) {
      bf16x8 af = *(const bf16x8*)&sm.t.y[s * 16 + l16][k0 + quad * 8];
#pragma unroll
      for (int nj = 0; nj < 6; ++nj) {
        bf16x8 wf = *(const bf16x8*)(Wt2 + (size_t)(nh + nj*16 + l16) * 192 + k0 + quad * 8);
        g1[nj] = __builtin_amdgcn_mfma_f32_16x16x32_bf16(wf, af, g1[nj], 0, 0, 0);
      }
    }
    const int tok = s * 16 + l16;
    const int token = T0 + tok;
#pragma unroll
    for (int nj = 0; nj < 6; ++nj) {
      const int nb = nh + nj * 16 + quad * 4;
      const ushort4 g4 = *(const ushort4*)(xz0 + (size_t)token * 384 + 192 + nb);
      ushort4 o;
      o.x = f2bf(g1[nj][0] * silu_f(bf2f(g4.x)));
      o.y = f2bf(g1[nj][1] * silu_f(bf2f(g4.y)));
      o.z = f2bf(g1[nj][2] * silu_f(bf2f(g4.z)));
      o.w = f2bf(g1[nj][3] * silu_f(bf2f(g4.w)));
      *(ushort4*)&sm.dlt[tok][nb] = o;
    }
  }
  __syncthreads();
  {
    // GEMM2 (out_proj, N=96) + residual -> out fp32
    const int s = wv >> 1;
    const int nh = (wv & 1) * 48;
    f32x4 g2[3];
#pragma unroll
    for (int j = 0; j < 3; ++j) g2[j] = z4;
#pragma unroll
    for (int k0 = 0; k0 < 192; k0 += 32) {
      bf16x8 af = *(const bf16x8*)&sm.dlt[s * 16 + l16][k0 + quad * 8];
#pragma unroll
      for (int nj = 0; nj < 3; ++nj) {
        bf16x8 wf = *(const bf16x8*)(Wt3 + (size_t)(nh + nj*16 + l16) * 192 + k0 + quad * 8);
        g2[nj] = __builtin_amdgcn_mfma_f32_16x16x32_bf16(wf, af, g2[nj], 0, 0, 0);
      }
    }
    const int token = T0 + s * 16 + l16;
#pragma unroll
    for (int nj = 0; nj < 3; ++nj) {
      const int nb = nh + nj * 16 + quad * 4;
      const float4 r4 = *(const float4*)(x + (size_t)token * 96 + nb);
      *(float4*)(out + (size_t)token * 96 + nb) =
          make_float4(g2[nj][0] + r4.x, g2[nj][1] + r4.y,
                      g2[nj][2] + r4.z, g2[nj][3] + r4.w);
    }
  }
}

// ---------------- launch ----------------
extern "C" void kernel_launch(void* const* d_in, const int* in_sizes, int n_in,
                              void* d_out, int out_size, void* d_ws, size_t ws_size,
                              hipStream_t stream)
{
  const float* x         = (const float*)d_in[0];
  const float* norm_w    = (const float*)d_in[1];
  const float* norm_b    = (const float*)d_in[2];
  const float* in_proj_w = (const float*)d_in[3];
  const float* conv2d_w  = (const float*)d_in[4];
  const float* m_in_proj = (const float*)d_in[5];
  const float* m_c1d_w   = (const float*)d_in[6];
  const float* m_c1d_b   = (const float*)d_in[7];
  const float* m_x_proj  = (const float*)d_in[8];
  const float* m_dt_w    = (const float*)d_in[9];
  const float* m_dt_b    = (const float*)d_in[10];
  const float* m_A_log   = (const float*)d_in[11];
  const float* m_D       = (const float*)d_in[12];
  const float* m_out_w   = (const float*)d_in[13];
  const float* out_w     = (const float*)d_in[14];
  float* out = (float*)d_out;

  char* wp = (char*)d_ws;
  auto alloc = [&](size_t bytes) {
    char* r = wp; wp += (bytes + 255) & ~(size_t)255; return r;
  };
  unsigned* bar  = (unsigned*)alloc(7 * 1024 * 4);   // 7 phases x 4KB
  ushort* Wt0    = (ushort*)alloc(36864 * 2);
  ushort* Wt1    = (ushort*)alloc(73728 * 2);
  ushort* Wt2    = (ushort*)alloc(36864 * 2);
  ushort* Wt3    = (ushort*)alloc(24576 * 2);
  ushort* Wxt    = (ushort*)alloc(9216 * 2);
  ushort* Wdtt   = (ushort*)alloc(6144 * 2);
  float*  cw1T   = (float*)alloc(576 * 4);
  float*  cw2T   = (float*)alloc(1728 * 4);
  ushort* xz0    = (ushort*)alloc((size_t)TT * 384 * 2);
  ushort* xz1    = (ushort*)alloc((size_t)TT * 384 * 2);
  float*  P      = (float*)alloc((size_t)BATCH * NCHUNK * QDN * 4);
  float*  E      = (float*)alloc((size_t)BATCH * NCHUNK * QDN * 4);
  float*  SP     = (float*)alloc((size_t)BATCH * NSUP * QDN * 4);
  float*  SE     = (float*)alloc((size_t)BATCH * NSUP * QDN * 4);
  float*  Hsup   = (float*)alloc((size_t)BATCH * NSUP * QDN * 4);
  float*  Hin    = (float*)alloc((size_t)BATCH * NCHUNK * QDN * 4);

  hipMemsetAsync(bar, 0, 7 * 1024 * 4, stream);
  mega_kernel<<<NB, 256, 0, stream>>>(
      x, norm_w, norm_b, in_proj_w, conv2d_w, m_in_proj, m_c1d_w, m_c1d_b,
      m_x_proj, m_dt_w, m_dt_b, m_A_log, m_D, m_out_w, out_w, out,
      bar, Wt0, Wt1, Wt2, Wt3, Wxt, Wdtt, cw1T, cw2T,
      xz0, xz1, P, E, SP, SE, Hsup, Hin);
}

// Round 9
// 239.515 us; speedup vs baseline: 7.8618x; 7.2997x over previous
//
#include <hip/hip_runtime.h>

#define DEV_INLINE __device__ __forceinline__

constexpr int BATCH = 2;
constexpr int HH = 96, WW = 96, CC = 96;
constexpr int DI = 192;
constexpr int NS = 16;
constexpr int LSEQ = HH * WW;        // 9216
constexpr int TT = BATCH * LSEQ;     // 18432
constexpr int CHUNK = 16;
constexpr int NCHUNK = LSEQ / CHUNK; // 576 per batch
constexpr int SUP = 24, NSUP = NCHUNK / SUP; // 24
constexpr int QDN = DI * NS;         // 3072

typedef __attribute__((ext_vector_type(8))) short bf16x8;
typedef __attribute__((ext_vector_type(4))) float f32x4;

DEV_INLINE float silu_f(float x) { return x / (1.f + __expf(-x)); }
DEV_INLINE float softplus_f(float x) {
  return fmaxf(x, 0.f) + log1pf(__expf(-fabsf(x)));
}
DEV_INLINE ushort f2bf(float f) {
  union { float f; unsigned u; } c; c.f = f;
  unsigned u = c.u + 0x7FFF + ((c.u >> 16) & 1);   // RNE
  return (ushort)(u >> 16);
}
DEV_INLINE float bf2f(ushort u) {
  union { unsigned u; float f; } c; c.u = ((unsigned)u) << 16; return c.f;
}

// ---------------- weight cast/transpose, coalesced READS (writes scatter) -------------
__global__ __launch_bounds__(256)
void castw_kernel(const float* __restrict__ w0, const float* __restrict__ w1,
                  const float* __restrict__ w2, const float* __restrict__ w3,
                  const float* __restrict__ wx, const float* __restrict__ wdt,
                  const float* __restrict__ wc1,
                  ushort* __restrict__ t0, ushort* __restrict__ t1,
                  ushort* __restrict__ t2, ushort* __restrict__ t3,
                  ushort* __restrict__ t4, ushort* __restrict__ t5,
                  float* __restrict__ cwT)
{
  int id = blockIdx.x * 256 + threadIdx.x;      // 187968 total
  if (id < 36864) {                              // in_proj W[96][384] -> [384][96]
    int k = id / 384, n = id % 384;
    t0[n * 96 + k] = f2bf(w0[id]);
  } else if (id < 110592) {                      // m_in W[192][384] -> [384][192]
    int j = id - 36864; int k = j / 384, n = j % 384;
    t1[n * 192 + k] = f2bf(w1[j]);
  } else if (id < 147456) {                      // m_out W[192][192] -> [192][192]
    int j = id - 110592; int k = j / 192, n = j % 192;
    t2[n * 192 + k] = f2bf(w2[j]);
  } else if (id < 165888) {                      // out W[192][96] -> [128][192]
    int j = id - 147456; int k = j / 96, n = j % 96;
    t3[n * 192 + k] = f2bf(w3[j]);
  } else if (id < 172032) {                      // zero rows 96..127
    int j = id - 165888;
    t3[96 * 192 + j] = 0;
  } else if (id < 180480) {                      // x_proj W[192][44] -> Wxt[48][192] permuted
    int j = id - 172032; int k = j / 44, c = j % 44;
    int r = (c < 12) ? (32 + c) : (c < 28 ? (c - 12) : (16 + c - 28));
    t4[r * 192 + k] = f2bf(wx[j]);
  } else if (id < 181248) {                      // zero rows 44..47
    int j = id - 180480;
    t4[44 * 192 + j] = 0;
  } else if (id < 183552) {                      // dt_proj W[12][192] -> Wdtt[192][32]
    int j = id - 181248; int r = j / 192, d = j % 192;
    t5[d * 32 + r] = f2bf(wdt[j]);
  } else if (id < 187392) {                      // zero cols 12..31
    int j = id - 183552; int d = j / 20, r = 12 + j % 20;
    t5[d * 32 + r] = 0;
  } else if (id < 187968) {                      // conv1d w[192][3] -> cwT[3][192]
    int j = id - 187392; int d = j / 3, k = j % 3;
    cwT[k * 192 + d] = wc1[j];
  }
}

// ---------------- fused LayerNorm + in_proj MFMA GEMM ----------------
__global__ __launch_bounds__(256)
void ln_inproj_kernel(const float* __restrict__ x, const float* __restrict__ nw,
                      const float* __restrict__ nbias, const ushort* __restrict__ Wt0,
                      ushort* __restrict__ xz0)
{
  __shared__ ushort sA[128][104];   // 2-way bank aliasing only (free)
  const int tid = threadIdx.x;
  const int m0 = blockIdx.x * 128;
  const int n0 = blockIdx.y * 64;
  {
    const int tok = tid >> 1, h = tid & 1;
    const float* xr = x + (size_t)(m0 + tok) * 96 + h * 48;
    float v[48];
    float s = 0.f, ss = 0.f;
#pragma unroll
    for (int i = 0; i < 12; ++i) {
      float4 t4 = *(const float4*)(xr + i * 4);
      v[i*4+0] = t4.x; v[i*4+1] = t4.y; v[i*4+2] = t4.z; v[i*4+3] = t4.w;
      s += (t4.x + t4.y) + (t4.z + t4.w);
      ss += (t4.x*t4.x + t4.y*t4.y) + (t4.z*t4.z + t4.w*t4.w);
    }
    s += __shfl_xor(s, 1);
    ss += __shfl_xor(ss, 1);
    float mean = s * (1.f/96.f);
    float var = ss * (1.f/96.f) - mean*mean;
    float rstd = rsqrtf(var + 1e-5f);
    const float* wr = nw + h*48;
    const float* br = nbias + h*48;
#pragma unroll
    for (int i = 0; i < 12; ++i) {
      float4 w4 = *(const float4*)(wr + i*4);
      float4 b4 = *(const float4*)(br + i*4);
      unsigned p0 = (unsigned)f2bf((v[i*4+0]-mean)*rstd*w4.x + b4.x)
                  | ((unsigned)f2bf((v[i*4+1]-mean)*rstd*w4.y + b4.y) << 16);
      unsigned p1 = (unsigned)f2bf((v[i*4+2]-mean)*rstd*w4.z + b4.z)
                  | ((unsigned)f2bf((v[i*4+3]-mean)*rstd*w4.w + b4.w) << 16);
      unsigned* dst = (unsigned*)&sA[tok][h*48 + i*4];
      dst[0] = p0; dst[1] = p1;
    }
  }
  __syncthreads();

  const int wid = tid >> 6, lane = tid & 63;
  const int wm = wid >> 1, wn = wid & 1;
  const int l16 = lane & 15, quad = lane >> 4;
  const f32x4 z4 = {0.f, 0.f, 0.f, 0.f};
  f32x4 acc[4][2];
#pragma unroll
  for (int i = 0; i < 4; ++i)
#pragma unroll
    for (int j = 0; j < 2; ++j) acc[i][j] = z4;

#pragma unroll
  for (int k0 = 0; k0 < 96; k0 += 32) {
    bf16x8 xf[4], wf[2];
#pragma unroll
    for (int i = 0; i < 4; ++i)
      xf[i] = *(const bf16x8*)&sA[wm*64 + i*16 + l16][k0 + quad*8];
#pragma unroll
    for (int j = 0; j < 2; ++j)
      wf[j] = *(const bf16x8*)(Wt0 + (size_t)(n0 + wn*32 + j*16 + l16) * 96 + k0 + quad*8);
#pragma unroll
    for (int i = 0; i < 4; ++i)
#pragma unroll
      for (int j = 0; j < 2; ++j)
        acc[i][j] = __builtin_amdgcn_mfma_f32_16x16x32_bf16(wf[j], xf[i], acc[i][j], 0, 0, 0);
  }
#pragma unroll
  for (int i = 0; i < 4; ++i) {
    const int token = m0 + wm*64 + i*16 + l16;
#pragma unroll
    for (int j = 0; j < 2; ++j) {
      const int nb = n0 + wn*32 + j*16 + quad*4;
      ushort4 o;
      o.x = f2bf(acc[i][j][0]); o.y = f2bf(acc[i][j][1]);
      o.z = f2bf(acc[i][j][2]); o.w = f2bf(acc[i][j][3]);
      *(ushort4*)(xz0 + (size_t)token * 384 + nb) = o;
    }
  }
}

// ---------------- depthwise 3x3 conv + SiLU, bf16 in/out ----------------
__global__ __launch_bounds__(256)
void conv2d_silu_kernel(const ushort* __restrict__ xz0, const float* __restrict__ w,
                        ushort* __restrict__ xc)
{
  __shared__ float ws[DI * 9];
  for (int i = threadIdx.x; i < DI * 9; i += 256) ws[i] = w[i];
  __syncthreads();
  int id = blockIdx.x * 256 + threadIdx.x;     // TT*48
  int dq = id % 48;
  int p  = id / 48;
  int j = p % WW;
  int i = (p / WW) % HH;
  int b = p / (WW * HH);
  int d = dq * 4;
  float a0 = 0.f, a1 = 0.f, a2 = 0.f, a3 = 0.f;
#pragma unroll
  for (int ki = 0; ki < 3; ++ki) {
    int ii = i + ki - 1;
    if (ii < 0 || ii >= HH) continue;
#pragma unroll
    for (int kj = 0; kj < 3; ++kj) {
      int jj = j + kj - 1;
      if (jj < 0 || jj >= WW) continue;
      const ushort4 v = *(const ushort4*)(xz0 + ((size_t)((b * HH + ii) * WW + jj)) * 384 + d);
      int wk = ki * 3 + kj;
      a0 = fmaf(bf2f(v.x), ws[(d + 0) * 9 + wk], a0);
      a1 = fmaf(bf2f(v.y), ws[(d + 1) * 9 + wk], a1);
      a2 = fmaf(bf2f(v.z), ws[(d + 2) * 9 + wk], a2);
      a3 = fmaf(bf2f(v.w), ws[(d + 3) * 9 + wk], a3);
    }
  }
  ushort4 o;
  o.x = f2bf(silu_f(a0)); o.y = f2bf(silu_f(a1));
  o.z = f2bf(silu_f(a2)); o.w = f2bf(silu_f(a3));
  *(ushort4*)(xc + (size_t)p * DI + d) = o;
}

// ---------------- bf16 MFMA GEMM (m_in_proj) ----------------
__global__ __launch_bounds__(256)
void mfma_gemm_kernel(const ushort* __restrict__ A, int lda,
                      const ushort* __restrict__ Bt, int ldb,
                      ushort* __restrict__ Cout, int ldc, int K)
{
  const int tid = threadIdx.x;
  const int wid = tid >> 6, lane = tid & 63;
  const int wm = wid >> 1, wn = wid & 1;
  const int m0 = blockIdx.x * 128 + wm * 64;
  const int n0 = blockIdx.y * 64 + wn * 32;
  const int l16 = lane & 15, quad = lane >> 4;

  f32x4 acc[4][2];
  const f32x4 z4 = {0.f, 0.f, 0.f, 0.f};
#pragma unroll
  for (int i = 0; i < 4; ++i)
#pragma unroll
    for (int j = 0; j < 2; ++j) acc[i][j] = z4;

  for (int k0 = 0; k0 < K; k0 += 32) {
    bf16x8 xf[4], wf[2];
#pragma unroll
    for (int i = 0; i < 4; ++i)
      xf[i] = *(const bf16x8*)(A + (size_t)(m0 + i * 16 + l16) * lda + k0 + quad * 8);
#pragma unroll
    for (int j = 0; j < 2; ++j)
      wf[j] = *(const bf16x8*)(Bt + (size_t)(n0 + j * 16 + l16) * ldb + k0 + quad * 8);
#pragma unroll
    for (int i = 0; i < 4; ++i)
#pragma unroll
      for (int j = 0; j < 2; ++j)
        acc[i][j] = __builtin_amdgcn_mfma_f32_16x16x32_bf16(wf[j], xf[i], acc[i][j], 0, 0, 0);
  }
#pragma unroll
  for (int i = 0; i < 4; ++i) {
    const int token = m0 + i * 16 + l16;
#pragma unroll
    for (int j = 0; j < 2; ++j) {
      const int nb = n0 + j * 16 + quad * 4;
      ushort4 o;
      o.x = f2bf(acc[i][j][0]); o.y = f2bf(acc[i][j][1]);
      o.z = f2bf(acc[i][j][2]); o.w = f2bf(acc[i][j][3]);
      *(ushort4*)(Cout + (size_t)token * ldc + nb) = o;
    }
  }
}

// ---------------- causal depthwise conv1d + bias + SiLU, bf16 ----------------
__global__ __launch_bounds__(256)
void conv1d_silu_kernel(const ushort* __restrict__ xz1, const float* __restrict__ cwT,
                        const float* __restrict__ bias, ushort* __restrict__ xm)
{
  int id = blockIdx.x * 256 + threadIdx.x;   // TT*48
  int dq = id % 48;
  int t  = id / 48;
  int l  = t % LSEQ;
  int d  = dq * 4;
  float4 b4 = *(const float4*)(bias + d);
  float a0 = b4.x, a1 = b4.y, a2 = b4.z, a3 = b4.w;
#pragma unroll
  for (int k = 0; k < 3; ++k) {
    if (l + k - 2 < 0) continue;
    const ushort4 v = *(const ushort4*)(xz1 + (size_t)(t + k - 2) * 384 + d);
    const float4 w4 = *(const float4*)(cwT + k * 192 + d);
    a0 = fmaf(bf2f(v.x), w4.x, a0);
    a1 = fmaf(bf2f(v.y), w4.y, a1);
    a2 = fmaf(bf2f(v.z), w4.z, a2);
    a3 = fmaf(bf2f(v.w), w4.w, a3);
  }
  ushort4 o;
  o.x = f2bf(silu_f(a0)); o.y = f2bf(silu_f(a1));
  o.z = f2bf(silu_f(a2)); o.w = f2bf(silu_f(a3));
  *(ushort4*)(xm + (size_t)t * DI + d) = o;
}

// ---------------- x_proj MFMA: wave-task = (16-token strip, tile{B,C,dt}) --------------
__global__ __launch_bounds__(256)
void xproj_kernel(const ushort* __restrict__ xmb, const ushort* __restrict__ Wxt,
                  float* __restrict__ xdbl_bc, ushort* __restrict__ dtpad)
{
  const int w = blockIdx.x * 4 + (threadIdx.x >> 6);   // 3456 wave-tasks
  const int lane = threadIdx.x & 63;
  const int s = w / 3, tile = w % 3;
  const int l16 = lane & 15, quad = lane >> 4;
  const int token = s * 16 + l16;

  f32x4 acc = {0.f, 0.f, 0.f, 0.f};
#pragma unroll
  for (int k0 = 0; k0 < 192; k0 += 32) {
    bf16x8 xf = *(const bf16x8*)(xmb + (size_t)token * DI + k0 + quad * 8);
    bf16x8 wf = *(const bf16x8*)(Wxt + (size_t)(tile * 16 + l16) * 192 + k0 + quad * 8);
    acc = __builtin_amdgcn_mfma_f32_16x16x32_bf16(wf, xf, acc, 0, 0, 0);
  }
  if (tile < 2) {
    *(float4*)(xdbl_bc + (size_t)token * 32 + tile * 16 + quad * 4) =
        make_float4(acc[0], acc[1], acc[2], acc[3]);
  } else {
    ushort4 o;
    o.x = f2bf(acc[0]); o.y = f2bf(acc[1]); o.z = f2bf(acc[2]); o.w = f2bf(acc[3]);
    *(ushort4*)(dtpad + (size_t)token * 32 + quad * 4) = o;
    *(ushort4*)(dtpad + (size_t)token * 32 + 16 + quad * 4) = make_ushort4(0, 0, 0, 0);
  }
}

// ---------------- dt_proj MFMA + softplus -> dlt bf16 ----------------
__global__ __launch_bounds__(256)
void dtproj_kernel(const ushort* __restrict__ dtpad, const ushort* __restrict__ Wdtt,
                   const float* __restrict__ bdt, ushort* __restrict__ dlt)
{
  const int w = blockIdx.x * 4 + (threadIdx.x >> 6);   // 3456
  const int lane = threadIdx.x & 63;
  const int s = w / 3, cg = w % 3;
  const int l16 = lane & 15, quad = lane >> 4;
  const int token = s * 16 + l16;
  const f32x4 z4 = {0.f, 0.f, 0.f, 0.f};

  bf16x8 dtf = *(const bf16x8*)(dtpad + (size_t)token * 32 + quad * 8);
  f32x4 acc[4];
#pragma unroll
  for (int jj = 0; jj < 4; ++jj) {
    bf16x8 wf = *(const bf16x8*)(Wdtt + (size_t)(cg * 64 + jj * 16 + l16) * 32 + quad * 8);
    acc[jj] = __builtin_amdgcn_mfma_f32_16x16x32_bf16(wf, dtf, z4, 0, 0, 0);
  }
#pragma unroll
  for (int jj = 0; jj < 4; ++jj) {
    const int nb = cg * 64 + jj * 16 + quad * 4;
    const float4 b4 = *(const float4*)(bdt + nb);
    ushort4 o;
    o.x = f2bf(softplus_f(acc[jj][0] + b4.x));
    o.y = f2bf(softplus_f(acc[jj][1] + b4.y));
    o.z = f2bf(softplus_f(acc[jj][2] + b4.z));
    o.w = f2bf(softplus_f(acc[jj][3] + b4.w));
    *(ushort4*)(dlt + (size_t)token * DI + nb) = o;
  }
}

// ---------------- scan1: chunk local recurrence; LDS-staged B; P/E layout q=j*192+d ---
__global__ __launch_bounds__(192)
void scan1_kernel(const ushort* __restrict__ dlt, const ushort* __restrict__ xmb,
                  const float* __restrict__ bc, const float* __restrict__ Alog,
                  float* __restrict__ P, float* __restrict__ E)
{
  __shared__ float sB[CHUNK][16];
  const int d = threadIdx.x;
  const int g = blockIdx.x % NCHUNK;
  const int b = blockIdx.x / NCHUNK;
  const int t0 = b * LSEQ + g * CHUNK;
  for (int i = threadIdx.x; i < CHUNK * 16; i += 192) {
    int l = i >> 4, j = i & 15;
    sB[l][j] = bc[(size_t)(t0 + l) * 32 + j];
  }
  float Av[16];
#pragma unroll
  for (int j = 0; j < 16; ++j) Av[j] = -__expf(Alog[d * 16 + j]);
  __syncthreads();
  float e[16];
#pragma unroll
  for (int j = 0; j < 16; ++j) e[j] = 0.f;
  float sdl = 0.f;
#pragma unroll 4
  for (int l = 0; l < CHUNK; ++l) {
    const int t = t0 + l;
    float dl = bf2f(dlt[(size_t)t * DI + d]);
    float u  = bf2f(xmb[(size_t)t * DI + d]);
    float du = dl * u;
    sdl += dl;
#pragma unroll
    for (int j = 0; j < 16; ++j) {
      float a = __expf(dl * Av[j]);
      e[j] = fmaf(a, e[j], du * sB[l][j]);
    }
  }
  size_t base = ((size_t)(b * NCHUNK + g)) * QDN + d;
#pragma unroll
  for (int j = 0; j < 16; ++j) {
    P[base + j * 192] = __expf(Av[j] * sdl);
    E[base + j * 192] = e[j];
  }
}

// ---------------- scan2a: per-super product/accum ----------------
__global__ __launch_bounds__(256)
void scan2a_kernel(const float* __restrict__ P, const float* __restrict__ E,
                   float* __restrict__ SP, float* __restrict__ SE)
{
  int id = blockIdx.x * 256 + threadIdx.x;  // BATCH*NSUP*QDN = 147456
  int q = id % QDN;
  int s = (id / QDN) % NSUP;
  int b = id / (QDN * NSUP);
  float cp = 1.f, ce = 0.f;
#pragma unroll 6
  for (int c = 0; c < SUP; ++c) {
    size_t idx = ((size_t)(b * NCHUNK + s * SUP + c)) * QDN + q;
    float p = P[idx], e = E[idx];
    ce = fmaf(p, ce, e);
    cp *= p;
  }
  SP[id] = cp; SE[id] = ce;
}

// ---------------- scan2b: serial over NSUP supers ----------------
__global__ __launch_bounds__(256)
void scan2b_kernel(const float* __restrict__ SP, const float* __restrict__ SE,
                   float* __restrict__ Hsup)
{
  int id = blockIdx.x * 256 + threadIdx.x;  // BATCH*QDN = 6144
  int q = id % QDN;
  int b = id / QDN;
  float carry = 0.f;
#pragma unroll
  for (int s = 0; s < NSUP; ++s) {
    size_t idx = ((size_t)(b * NSUP + s)) * QDN + q;
    Hsup[idx] = carry;
    carry = fmaf(SP[idx], carry, SE[idx]);
  }
}

// ---------------- scan2c: expand to per-chunk inbound ----------------
__global__ __launch_bounds__(256)
void scan2c_kernel(const float* __restrict__ P, const float* __restrict__ E,
                   const float* __restrict__ Hsup, float* __restrict__ Hin)
{
  int id = blockIdx.x * 256 + threadIdx.x;  // 147456
  int q = id % QDN;
  int s = (id / QDN) % NSUP;
  int b = id / (QDN * NSUP);
  float h = Hsup[id];
#pragma unroll 6
  for (int c = 0; c < SUP; ++c) {
    size_t idx = ((size_t)(b * NCHUNK + s * SUP + c)) * QDN + q;
    Hin[idx] = h;
    h = fmaf(P[idx], h, E[idx]);
  }
}

// ---------------- scan3: replay + y + gate -> bf16; LDS-staged B,C ----------------
__global__ __launch_bounds__(192)
void scan3_kernel(const ushort* __restrict__ dlt, const ushort* __restrict__ xmb,
                  const float* __restrict__ bc, const float* __restrict__ Alog,
                  const float* __restrict__ Dv, const ushort* __restrict__ xz1,
                  const float* __restrict__ Hin, ushort* __restrict__ yout)
{
  __shared__ float sBC[CHUNK][32];
  const int d = threadIdx.x;
  const int g = blockIdx.x % NCHUNK;
  const int b = blockIdx.x / NCHUNK;
  const int t0 = b * LSEQ + g * CHUNK;
  for (int i = threadIdx.x; i < CHUNK * 32; i += 192) {
    int l = i >> 5, j = i & 31;
    sBC[l][j] = bc[(size_t)(t0 + l) * 32 + j];
  }
  float Av[16];
#pragma unroll
  for (int j = 0; j < 16; ++j) Av[j] = -__expf(Alog[d * 16 + j]);
  const float Dd = Dv[d];
  float h[16];
  {
    size_t hb = ((size_t)(b * NCHUNK + g)) * QDN + d;
#pragma unroll
    for (int j = 0; j < 16; ++j) h[j] = Hin[hb + j * 192];
  }
  __syncthreads();
#pragma unroll 4
  for (int l = 0; l < CHUNK; ++l) {
    const int t = t0 + l;
    float dl = bf2f(dlt[(size_t)t * DI + d]);
    float u  = bf2f(xmb[(size_t)t * DI + d]);
    float z  = bf2f(xz1[(size_t)t * 384 + 192 + d]);
    float du = dl * u;
    float y0 = 0.f, y1 = 0.f, y2 = 0.f, y3 = 0.f;
#pragma unroll
    for (int j = 0; j < 16; ++j) {
      float a = __expf(dl * Av[j]);
      h[j] = fmaf(a, h[j], du * sBC[l][j]);
      float hc = h[j] * sBC[l][16 + j];
      if ((j & 3) == 0) y0 += hc;
      else if ((j & 3) == 1) y1 += hc;
      else if ((j & 3) == 2) y2 += hc;
      else y3 += hc;
    }
    float y = (y0 + y1) + (y2 + y3) + u * Dd;
    yout[(size_t)t * DI + d] = f2bf(y * silu_f(z));
  }
}

// ---------------- fused m_out_proj (silu gate) + out_proj (+residual) ----------------
__global__ __launch_bounds__(256)
void outproj_kernel(const ushort* __restrict__ yfin, const ushort* __restrict__ Wt2,
                    const ushort* __restrict__ xz0, const ushort* __restrict__ Wt3,
                    const float* __restrict__ x, float* __restrict__ out)
{
  __shared__ ushort yg_s[32][204];
  const int tid = threadIdx.x;
  const int wid = tid >> 6, lane = tid & 63;
  const int wm = wid >> 1, wn = wid & 1;
  const int l16 = lane & 15, quad = lane >> 4;
  const int m0 = blockIdx.x * 32;
  const f32x4 z4 = {0.f, 0.f, 0.f, 0.f};

  f32x4 acc[6];
#pragma unroll
  for (int j = 0; j < 6; ++j) acc[j] = z4;
  const int mt = m0 + wm * 16 + l16;
#pragma unroll
  for (int k0 = 0; k0 < 192; k0 += 32) {
    bf16x8 af = *(const bf16x8*)(yfin + (size_t)mt * 192 + k0 + quad * 8);
#pragma unroll
    for (int nj = 0; nj < 6; ++nj) {
      bf16x8 wf = *(const bf16x8*)(Wt2 + (size_t)(wn * 96 + nj * 16 + l16) * 192 + k0 + quad * 8);
      acc[nj] = __builtin_amdgcn_mfma_f32_16x16x32_bf16(wf, af, acc[nj], 0, 0, 0);
    }
  }
#pragma unroll
  for (int nj = 0; nj < 6; ++nj) {
    const int tok = wm * 16 + l16;
    const int nb = wn * 96 + nj * 16 + quad * 4;
    const ushort4 g4 = *(const ushort4*)(xz0 + (size_t)(m0 + tok) * 384 + 192 + nb);
    float v0 = acc[nj][0] * silu_f(bf2f(g4.x));
    float v1 = acc[nj][1] * silu_f(bf2f(g4.y));
    float v2 = acc[nj][2] * silu_f(bf2f(g4.z));
    float v3 = acc[nj][3] * silu_f(bf2f(g4.w));
    unsigned p0 = (unsigned)f2bf(v0) | ((unsigned)f2bf(v1) << 16);
    unsigned p1 = (unsigned)f2bf(v2) | ((unsigned)f2bf(v3) << 16);
    unsigned* dst = (unsigned*)&yg_s[tok][nb];
    dst[0] = p0; dst[1] = p1;
  }
  __syncthreads();

  f32x4 acc2[3];
#pragma unroll
  for (int j = 0; j < 3; ++j) acc2[j] = z4;
#pragma unroll
  for (int k0 = 0; k0 < 192; k0 += 32) {
    bf16x8 af = *(const bf16x8*)&yg_s[wm * 16 + l16][k0 + quad * 8];
#pragma unroll
    for (int nj = 0; nj < 3; ++nj) {
      bf16x8 wf = *(const bf16x8*)(Wt3 + (size_t)(wn * 48 + nj * 16 + l16) * 192 + k0 + quad * 8);
      acc2[nj] = __builtin_amdgcn_mfma_f32_16x16x32_bf16(wf, af, acc2[nj], 0, 0, 0);
    }
  }
#pragma unroll
  for (int nj = 0; nj < 3; ++nj) {
    const int tok = wm * 16 + l16;
    const int nb = wn * 48 + nj * 16 + quad * 4;
    const float4 r4 = *(const float4*)(x + (size_t)(m0 + tok) * 96 + nb);
    *(float4*)(out + (size_t)(m0 + tok) * 96 + nb) =
        make_float4(acc2[nj][0] + r4.x, acc2[nj][1] + r4.y,
                    acc2[nj][2] + r4.z, acc2[nj][3] + r4.w);
  }
}

// ---------------- launch ----------------
extern "C" void kernel_launch(void* const* d_in, const int* in_sizes, int n_in,
                              void* d_out, int out_size, void* d_ws, size_t ws_size,
                              hipStream_t stream)
{
  const float* x         = (const float*)d_in[0];
  const float* norm_w    = (const float*)d_in[1];
  const float* norm_b    = (const float*)d_in[2];
  const float* in_proj_w = (const float*)d_in[3];
  const float* conv2d_w  = (const float*)d_in[4];
  const float* m_in_proj = (const float*)d_in[5];
  const float* m_c1d_w   = (const float*)d_in[6];
  const float* m_c1d_b   = (const float*)d_in[7];
  const float* m_x_proj  = (const float*)d_in[8];
  const float* m_dt_w    = (const float*)d_in[9];
  const float* m_dt_b    = (const float*)d_in[10];
  const float* m_A_log   = (const float*)d_in[11];
  const float* m_D       = (const float*)d_in[12];
  const float* m_out_w   = (const float*)d_in[13];
  const float* out_w     = (const float*)d_in[14];
  float* out = (float*)d_out;

  char* wp = (char*)d_ws;
  auto alloc = [&](size_t bytes) {
    char* r = wp; wp += (bytes + 255) & ~(size_t)255; return r;
  };
  ushort* Wt0    = (ushort*)alloc(36864 * 2);      // [384][96]
  ushort* Wt1    = (ushort*)alloc(73728 * 2);      // [384][192]
  ushort* Wt2    = (ushort*)alloc(36864 * 2);      // [192][192]
  ushort* Wt3    = (ushort*)alloc(24576 * 2);      // [128][192]
  ushort* Wxt    = (ushort*)alloc(9216 * 2);       // [48][192]
  ushort* Wdtt   = (ushort*)alloc(6144 * 2);       // [192][32]
  float*  cw1T   = (float*)alloc(576 * 4);         // [3][192]
  ushort* xz0    = (ushort*)alloc((size_t)TT * 384 * 2);
  ushort* xc_bf  = (ushort*)alloc((size_t)TT * 192 * 2);
  ushort* xz1    = (ushort*)alloc((size_t)TT * 384 * 2);
  ushort* xmb_bf = (ushort*)alloc((size_t)TT * 192 * 2);
  ushort* dtpad  = (ushort*)alloc((size_t)TT * 32 * 2);
  float*  bc     = (float*)alloc((size_t)TT * 32 * 4);
  ushort* dlt    = (ushort*)alloc((size_t)TT * 192 * 2);
  float*  P      = (float*)alloc((size_t)BATCH * NCHUNK * QDN * 4);
  float*  E      = (float*)alloc((size_t)BATCH * NCHUNK * QDN * 4);
  float*  SP     = (float*)alloc((size_t)BATCH * NSUP * QDN * 4);
  float*  SE     = (float*)alloc((size_t)BATCH * NSUP * QDN * 4);
  float*  Hsup   = (float*)alloc((size_t)BATCH * NSUP * QDN * 4);
  float*  Hin    = (float*)alloc((size_t)BATCH * NCHUNK * QDN * 4);
  ushort* yfin   = (ushort*)alloc((size_t)TT * 192 * 2);

  castw_kernel<<<735, 256, 0, stream>>>(in_proj_w, m_in_proj, m_out_w, out_w,
                                        m_x_proj, m_dt_w, m_c1d_w,
                                        Wt0, Wt1, Wt2, Wt3, Wxt, Wdtt, cw1T);
  ln_inproj_kernel<<<dim3(TT / 128, 6), 256, 0, stream>>>(x, norm_w, norm_b, Wt0, xz0);
  conv2d_silu_kernel<<<TT * 48 / 256, 256, 0, stream>>>(xz0, conv2d_w, xc_bf);
  mfma_gemm_kernel<<<dim3(TT / 128, 6), 256, 0, stream>>>(xc_bf, 192, Wt1, 192, xz1, 384, 192);
  conv1d_silu_kernel<<<TT * 48 / 256, 256, 0, stream>>>(xz1, cw1T, m_c1d_b, xmb_bf);
  xproj_kernel<<<TT / 16 * 3 / 4, 256, 0, stream>>>(xmb_bf, Wxt, bc, dtpad);
  dtproj_kernel<<<TT / 16 * 3 / 4, 256, 0, stream>>>(dtpad, Wdtt, m_dt_b, dlt);
  scan1_kernel<<<BATCH * NCHUNK, 192, 0, stream>>>(dlt, xmb_bf, bc, m_A_log, P, E);
  scan2a_kernel<<<BATCH * NSUP * QDN / 256, 256, 0, stream>>>(P, E, SP, SE);
  scan2b_kernel<<<BATCH * QDN / 256, 256, 0, stream>>>(SP, SE, Hsup);
  scan2c_kernel<<<BATCH * NSUP * QDN / 256, 256, 0, stream>>>(P, E, Hsup, Hin);
  scan3_kernel<<<BATCH * NCHUNK, 192, 0, stream>>>(dlt, xmb_bf, bc, m_A_log, m_D, xz1, Hin, yfin);
  outproj_kernel<<<TT / 32, 256, 0, stream>>>(yfin, Wt2, xz0, Wt3, x, out);
}

// Round 10
// 237.099 us; speedup vs baseline: 7.9419x; 1.0102x over previous
//
#include <hip/hip_runtime.h>

#define DEV_INLINE __device__ __forceinline__

constexpr int BATCH = 2;
constexpr int HH = 96, WW = 96, CC = 96;
constexpr int DI = 192;
constexpr int NS = 16;
constexpr int LSEQ = HH * WW;        // 9216
constexpr int TT = BATCH * LSEQ;     // 18432
constexpr int CHUNK = 16;
constexpr int NCHUNK = LSEQ / CHUNK; // 576 per batch
constexpr int SUP = 24, NSUP = NCHUNK / SUP; // 24
constexpr int QDN = DI * NS;         // 3072

typedef __attribute__((ext_vector_type(8))) short bf16x8;
typedef __attribute__((ext_vector_type(4))) float f32x4;

DEV_INLINE float silu_f(float x) { return x / (1.f + __expf(-x)); }
DEV_INLINE float softplus_f(float x) {
  return fmaxf(x, 0.f) + log1pf(__expf(-fabsf(x)));
}
DEV_INLINE ushort f2bf(float f) {
  union { float f; unsigned u; } c; c.f = f;
  unsigned u = c.u + 0x7FFF + ((c.u >> 16) & 1);   // RNE
  return (ushort)(u >> 16);
}
DEV_INLINE float bf2f(ushort u) {
  union { unsigned u; float f; } c; c.u = ((unsigned)u) << 16; return c.f;
}

// ---------------- weight cast/transpose, coalesced READS ----------------
__global__ __launch_bounds__(256)
void castw_kernel(const float* __restrict__ w0, const float* __restrict__ w1,
                  const float* __restrict__ w2, const float* __restrict__ w3,
                  const float* __restrict__ wx, const float* __restrict__ wdt,
                  const float* __restrict__ wc1,
                  ushort* __restrict__ t0, ushort* __restrict__ t1,
                  ushort* __restrict__ t2, ushort* __restrict__ t3,
                  ushort* __restrict__ t4, ushort* __restrict__ t5,
                  float* __restrict__ cwT)
{
  int id = blockIdx.x * 256 + threadIdx.x;      // 187968 total
  if (id < 36864) {                              // in_proj W[96][384] -> [384][96]
    int k = id / 384, n = id % 384;
    t0[n * 96 + k] = f2bf(w0[id]);
  } else if (id < 110592) {                      // m_in W[192][384] -> [384][192]
    int j = id - 36864; int k = j / 384, n = j % 384;
    t1[n * 192 + k] = f2bf(w1[j]);
  } else if (id < 147456) {                      // m_out W[192][192] -> [192][192]
    int j = id - 110592; int k = j / 192, n = j % 192;
    t2[n * 192 + k] = f2bf(w2[j]);
  } else if (id < 165888) {                      // out W[192][96] -> [128][192]
    int j = id - 147456; int k = j / 96, n = j % 96;
    t3[n * 192 + k] = f2bf(w3[j]);
  } else if (id < 172032) {                      // zero rows 96..127
    int j = id - 165888;
    t3[96 * 192 + j] = 0;
  } else if (id < 180480) {                      // x_proj W[192][44] -> Wxt[48][192] permuted
    int j = id - 172032; int k = j / 44, c = j % 44;
    int r = (c < 12) ? (32 + c) : (c < 28 ? (c - 12) : (16 + c - 28));
    t4[r * 192 + k] = f2bf(wx[j]);
  } else if (id < 181248) {                      // zero rows 44..47
    int j = id - 180480;
    t4[44 * 192 + j] = 0;
  } else if (id < 183552) {                      // dt_proj W[12][192] -> Wdtt[192][32]
    int j = id - 181248; int r = j / 192, d = j % 192;
    t5[d * 32 + r] = f2bf(wdt[j]);
  } else if (id < 187392) {                      // zero cols 12..31
    int j = id - 183552; int d = j / 20, r = 12 + j % 20;
    t5[d * 32 + r] = 0;
  } else if (id < 187968) {                      // conv1d w[192][3] -> cwT[3][192]
    int j = id - 187392; int d = j / 3, k = j % 3;
    cwT[k * 192 + d] = wc1[j];
  }
}

// ---------------- fused LayerNorm + in_proj MFMA GEMM ----------------
__global__ __launch_bounds__(256)
void ln_inproj_kernel(const float* __restrict__ x, const float* __restrict__ nw,
                      const float* __restrict__ nbias, const ushort* __restrict__ Wt0,
                      ushort* __restrict__ xz0)
{
  __shared__ ushort sA[128][104];
  const int tid = threadIdx.x;
  const int m0 = blockIdx.x * 128;
  const int n0 = blockIdx.y * 64;
  {
    const int tok = tid >> 1, h = tid & 1;
    const float* xr = x + (size_t)(m0 + tok) * 96 + h * 48;
    float v[48];
    float s = 0.f, ss = 0.f;
#pragma unroll
    for (int i = 0; i < 12; ++i) {
      float4 t4 = *(const float4*)(xr + i * 4);
      v[i*4+0] = t4.x; v[i*4+1] = t4.y; v[i*4+2] = t4.z; v[i*4+3] = t4.w;
      s += (t4.x + t4.y) + (t4.z + t4.w);
      ss += (t4.x*t4.x + t4.y*t4.y) + (t4.z*t4.z + t4.w*t4.w);
    }
    s += __shfl_xor(s, 1);
    ss += __shfl_xor(ss, 1);
    float mean = s * (1.f/96.f);
    float var = ss * (1.f/96.f) - mean*mean;
    float rstd = rsqrtf(var + 1e-5f);
    const float* wr = nw + h*48;
    const float* br = nbias + h*48;
#pragma unroll
    for (int i = 0; i < 12; ++i) {
      float4 w4 = *(const float4*)(wr + i*4);
      float4 b4 = *(const float4*)(br + i*4);
      unsigned p0 = (unsigned)f2bf((v[i*4+0]-mean)*rstd*w4.x + b4.x)
                  | ((unsigned)f2bf((v[i*4+1]-mean)*rstd*w4.y + b4.y) << 16);
      unsigned p1 = (unsigned)f2bf((v[i*4+2]-mean)*rstd*w4.z + b4.z)
                  | ((unsigned)f2bf((v[i*4+3]-mean)*rstd*w4.w + b4.w) << 16);
      unsigned* dst = (unsigned*)&sA[tok][h*48 + i*4];
      dst[0] = p0; dst[1] = p1;
    }
  }
  __syncthreads();

  const int wid = tid >> 6, lane = tid & 63;
  const int wm = wid >> 1, wn = wid & 1;
  const int l16 = lane & 15, quad = lane >> 4;
  const f32x4 z4 = {0.f, 0.f, 0.f, 0.f};
  f32x4 acc[4][2];
#pragma unroll
  for (int i = 0; i < 4; ++i)
#pragma unroll
    for (int j = 0; j < 2; ++j) acc[i][j] = z4;

#pragma unroll
  for (int k0 = 0; k0 < 96; k0 += 32) {
    bf16x8 xf[4], wf[2];
#pragma unroll
    for (int i = 0; i < 4; ++i)
      xf[i] = *(const bf16x8*)&sA[wm*64 + i*16 + l16][k0 + quad*8];
#pragma unroll
    for (int j = 0; j < 2; ++j)
      wf[j] = *(const bf16x8*)(Wt0 + (size_t)(n0 + wn*32 + j*16 + l16) * 96 + k0 + quad*8);
#pragma unroll
    for (int i = 0; i < 4; ++i)
#pragma unroll
      for (int j = 0; j < 2; ++j)
        acc[i][j] = __builtin_amdgcn_mfma_f32_16x16x32_bf16(wf[j], xf[i], acc[i][j], 0, 0, 0);
  }
#pragma unroll
  for (int i = 0; i < 4; ++i) {
    const int token = m0 + wm*64 + i*16 + l16;
#pragma unroll
    for (int j = 0; j < 2; ++j) {
      const int nb = n0 + wn*32 + j*16 + quad*4;
      ushort4 o;
      o.x = f2bf(acc[i][j][0]); o.y = f2bf(acc[i][j][1]);
      o.z = f2bf(acc[i][j][2]); o.w = f2bf(acc[i][j][3]);
      *(ushort4*)(xz0 + (size_t)token * 384 + nb) = o;
    }
  }
}

// ---------------- depthwise 3x3 conv + SiLU, bf16 in/out ----------------
__global__ __launch_bounds__(256)
void conv2d_silu_kernel(const ushort* __restrict__ xz0, const float* __restrict__ w,
                        ushort* __restrict__ xc)
{
  __shared__ float ws[DI * 9];
  for (int i = threadIdx.x; i < DI * 9; i += 256) ws[i] = w[i];
  __syncthreads();
  int id = blockIdx.x * 256 + threadIdx.x;     // TT*48
  int dq = id % 48;
  int p  = id / 48;
  int j = p % WW;
  int i = (p / WW) % HH;
  int b = p / (WW * HH);
  int d = dq * 4;
  float a0 = 0.f, a1 = 0.f, a2 = 0.f, a3 = 0.f;
#pragma unroll
  for (int ki = 0; ki < 3; ++ki) {
    int ii = i + ki - 1;
    if (ii < 0 || ii >= HH) continue;
#pragma unroll
    for (int kj = 0; kj < 3; ++kj) {
      int jj = j + kj - 1;
      if (jj < 0 || jj >= WW) continue;
      const ushort4 v = *(const ushort4*)(xz0 + ((size_t)((b * HH + ii) * WW + jj)) * 384 + d);
      int wk = ki * 3 + kj;
      a0 = fmaf(bf2f(v.x), ws[(d + 0) * 9 + wk], a0);
      a1 = fmaf(bf2f(v.y), ws[(d + 1) * 9 + wk], a1);
      a2 = fmaf(bf2f(v.z), ws[(d + 2) * 9 + wk], a2);
      a3 = fmaf(bf2f(v.w), ws[(d + 3) * 9 + wk], a3);
    }
  }
  ushort4 o;
  o.x = f2bf(silu_f(a0)); o.y = f2bf(silu_f(a1));
  o.z = f2bf(silu_f(a2)); o.w = f2bf(silu_f(a3));
  *(ushort4*)(xc + (size_t)p * DI + d) = o;
}

// ---------------- bf16 MFMA GEMM (m_in_proj) ----------------
__global__ __launch_bounds__(256)
void mfma_gemm_kernel(const ushort* __restrict__ A, int lda,
                      const ushort* __restrict__ Bt, int ldb,
                      ushort* __restrict__ Cout, int ldc, int K)
{
  const int tid = threadIdx.x;
  const int wid = tid >> 6, lane = tid & 63;
  const int wm = wid >> 1, wn = wid & 1;
  const int m0 = blockIdx.x * 128 + wm * 64;
  const int n0 = blockIdx.y * 64 + wn * 32;
  const int l16 = lane & 15, quad = lane >> 4;

  f32x4 acc[4][2];
  const f32x4 z4 = {0.f, 0.f, 0.f, 0.f};
#pragma unroll
  for (int i = 0; i < 4; ++i)
#pragma unroll
    for (int j = 0; j < 2; ++j) acc[i][j] = z4;

  for (int k0 = 0; k0 < K; k0 += 32) {
    bf16x8 xf[4], wf[2];
#pragma unroll
    for (int i = 0; i < 4; ++i)
      xf[i] = *(const bf16x8*)(A + (size_t)(m0 + i * 16 + l16) * lda + k0 + quad * 8);
#pragma unroll
    for (int j = 0; j < 2; ++j)
      wf[j] = *(const bf16x8*)(Bt + (size_t)(n0 + j * 16 + l16) * ldb + k0 + quad * 8);
#pragma unroll
    for (int i = 0; i < 4; ++i)
#pragma unroll
      for (int j = 0; j < 2; ++j)
        acc[i][j] = __builtin_amdgcn_mfma_f32_16x16x32_bf16(wf[j], xf[i], acc[i][j], 0, 0, 0);
  }
#pragma unroll
  for (int i = 0; i < 4; ++i) {
    const int token = m0 + i * 16 + l16;
#pragma unroll
    for (int j = 0; j < 2; ++j) {
      const int nb = n0 + j * 16 + quad * 4;
      ushort4 o;
      o.x = f2bf(acc[i][j][0]); o.y = f2bf(acc[i][j][1]);
      o.z = f2bf(acc[i][j][2]); o.w = f2bf(acc[i][j][3]);
      *(ushort4*)(Cout + (size_t)token * ldc + nb) = o;
    }
  }
}

// ---------------- fused mamba prep + chunk-local scan ----------------
// Block: 32 tokens (= 2 chunks), 256 threads. Grid 576.
// conv1d+SiLU -> LDS; x_proj B/C + dt(shfl)+dt_proj MFMA (role waves);
// scan1 from LDS -> packed bf16 P|E.
__global__ __launch_bounds__(256)
void mprep_kernel(const ushort* __restrict__ xz1, const float* __restrict__ cwT,
                  const float* __restrict__ cb, const ushort* __restrict__ Wxt,
                  const ushort* __restrict__ Wdtt, const float* __restrict__ bdt,
                  const float* __restrict__ Alog,
                  ushort* __restrict__ xmb, ushort* __restrict__ dlt,
                  float* __restrict__ bc, unsigned* __restrict__ PE)
{
  __shared__ ushort sxm[32][204];
  __shared__ ushort sdlt[32][204];
  __shared__ float sbc[32][36];
  const int tid = threadIdx.x;
  const int bid = blockIdx.x;
  const int T0 = bid * 32;
  const f32x4 z4 = {0.f, 0.f, 0.f, 0.f};

  // phase a: causal conv1d + bias + SiLU
  for (int task = tid; task < 1536; task += 256) {
    int dq = task % 48, tok = task / 48;
    int t = T0 + tok, l = t % LSEQ;
    int d = dq * 4;
    float4 b4 = *(const float4*)(cb + d);
    float a0 = b4.x, a1 = b4.y, a2 = b4.z, a3 = b4.w;
#pragma unroll
    for (int k = 0; k < 3; ++k) {
      if (l + k - 2 < 0) continue;
      const ushort4 v = *(const ushort4*)(xz1 + (size_t)(t + k - 2) * 384 + d);
      const float4 w4 = *(const float4*)(cwT + k * 192 + d);
      a0 = fmaf(bf2f(v.x), w4.x, a0);
      a1 = fmaf(bf2f(v.y), w4.y, a1);
      a2 = fmaf(bf2f(v.z), w4.z, a2);
      a3 = fmaf(bf2f(v.w), w4.w, a3);
    }
    ushort4 o;
    o.x = f2bf(silu_f(a0)); o.y = f2bf(silu_f(a1));
    o.z = f2bf(silu_f(a2)); o.w = f2bf(silu_f(a3));
    *(ushort4*)&sxm[tok][d] = o;
    *(ushort4*)(xmb + (size_t)t * DI + d) = o;
  }
  __syncthreads();

  // phase b: x_proj (B,C | dt->dt_proj) by wave role
  {
    const int wv = tid >> 6, lane = tid & 63;
    const int l16 = lane & 15, quad = lane >> 4;
    const int s = wv & 1, role = wv >> 1;
    const int tokb = s * 16;
    if (role == 0) {
      f32x4 aB = z4, aC = z4;
#pragma unroll
      for (int k0 = 0; k0 < 192; k0 += 32) {
        bf16x8 uf = *(const bf16x8*)&sxm[tokb + l16][k0 + quad * 8];
        bf16x8 wB = *(const bf16x8*)(Wxt + (size_t)(l16) * 192 + k0 + quad * 8);
        bf16x8 wC = *(const bf16x8*)(Wxt + (size_t)(16 + l16) * 192 + k0 + quad * 8);
        aB = __builtin_amdgcn_mfma_f32_16x16x32_bf16(wB, uf, aB, 0, 0, 0);
        aC = __builtin_amdgcn_mfma_f32_16x16x32_bf16(wC, uf, aC, 0, 0, 0);
      }
      float4 vB = make_float4(aB[0], aB[1], aB[2], aB[3]);
      float4 vC = make_float4(aC[0], aC[1], aC[2], aC[3]);
      *(float4*)&sbc[tokb + l16][quad * 4] = vB;
      *(float4*)&sbc[tokb + l16][16 + quad * 4] = vC;
      *(float4*)(bc + (size_t)(T0 + tokb + l16) * 32 + quad * 4) = vB;
      *(float4*)(bc + (size_t)(T0 + tokb + l16) * 32 + 16 + quad * 4) = vC;
    } else {
      f32x4 aD = z4;
#pragma unroll
      for (int k0 = 0; k0 < 192; k0 += 32) {
        bf16x8 uf = *(const bf16x8*)&sxm[tokb + l16][k0 + quad * 8];
        bf16x8 wD = *(const bf16x8*)(Wxt + (size_t)(32 + l16) * 192 + k0 + quad * 8);
        aD = __builtin_amdgcn_mfma_f32_16x16x32_bf16(wD, uf, aD, 0, 0, 0);
      }
      bf16x8 dtf;
#pragma unroll
      for (int j = 0; j < 8; ++j) {
        int n = quad * 8 + j;
        int src = ((n >> 2) & 3) * 16 + l16;
        float tv = __shfl(aD[j & 3], src);
        dtf[j] = (short)((n < 16) ? f2bf(tv) : (ushort)0);
      }
      f32x4 a2[12];
#pragma unroll
      for (int jj = 0; jj < 12; ++jj) {
        bf16x8 wf = *(const bf16x8*)(Wdtt + (size_t)(jj * 16 + l16) * 32 + quad * 8);
        a2[jj] = __builtin_amdgcn_mfma_f32_16x16x32_bf16(wf, dtf, z4, 0, 0, 0);
      }
#pragma unroll
      for (int jj = 0; jj < 12; ++jj) {
        const int nb = jj * 16 + quad * 4;
        const float4 b4 = *(const float4*)(bdt + nb);
        ushort4 o;
        o.x = f2bf(softplus_f(a2[jj][0] + b4.x));
        o.y = f2bf(softplus_f(a2[jj][1] + b4.y));
        o.z = f2bf(softplus_f(a2[jj][2] + b4.z));
        o.w = f2bf(softplus_f(a2[jj][3] + b4.w));
        *(ushort4*)&sdlt[tokb + l16][nb] = o;
        *(ushort4*)(dlt + (size_t)(T0 + tokb + l16) * DI + nb) = o;
      }
    }
  }
  __syncthreads();

  // phase c: scan1 over 2 chunks of 16, all inputs in LDS -> packed P|E
  for (int task = tid; task < 384; task += 256) {
    const int d = task % 192, c = task / 192;
    float Av[16];
#pragma unroll
    for (int j = 0; j < 16; ++j) Av[j] = -__expf(Alog[d * 16 + j]);
    float e[16];
#pragma unroll
    for (int j = 0; j < 16; ++j) e[j] = 0.f;
    float sdl = 0.f;
    for (int l = 0; l < CHUNK; ++l) {
      const int tl = c * 16 + l;
      float dl = bf2f(sdlt[tl][d]);
      float u  = bf2f(sxm[tl][d]);
      const float4 B0 = *(const float4*)&sbc[tl][0];
      const float4 B1 = *(const float4*)&sbc[tl][4];
      const float4 B2 = *(const float4*)&sbc[tl][8];
      const float4 B3 = *(const float4*)&sbc[tl][12];
      const float Bv[16] = {B0.x, B0.y, B0.z, B0.w, B1.x, B1.y, B1.z, B1.w,
                            B2.x, B2.y, B2.z, B2.w, B3.x, B3.y, B3.z, B3.w};
      float du = dl * u;
      sdl += dl;
#pragma unroll
      for (int j = 0; j < 16; ++j) {
        float a = __expf(dl * Av[j]);
        e[j] = fmaf(a, e[j], du * Bv[j]);
      }
    }
    const int batch = bid / 288;
    const int gci = (bid % 288) * 2 + c;
    size_t base = ((size_t)(batch * NCHUNK + gci)) * QDN + d;
#pragma unroll
    for (int j = 0; j < 16; ++j) {
      unsigned p = f2bf(__expf(Av[j] * sdl));
      unsigned ev = f2bf(e[j]);
      PE[base + j * 192] = (p << 16) | ev;
    }
  }
}

// ---------------- scan2a: per-super product/accum (packed P|E in) ----------------
__global__ __launch_bounds__(256)
void scan2a_kernel(const unsigned* __restrict__ PE,
                   float* __restrict__ SP, float* __restrict__ SE)
{
  int id = blockIdx.x * 256 + threadIdx.x;  // BATCH*NSUP*QDN = 147456
  int q = id % QDN;
  int s = (id / QDN) % NSUP;
  int b = id / (QDN * NSUP);
  float cp = 1.f, ce = 0.f;
#pragma unroll 6
  for (int c = 0; c < SUP; ++c) {
    unsigned pe = PE[((size_t)(b * NCHUNK + s * SUP + c)) * QDN + q];
    float p = bf2f((ushort)(pe >> 16));
    float e = bf2f((ushort)(pe & 0xFFFF));
    ce = fmaf(p, ce, e);
    cp *= p;
  }
  SP[id] = cp; SE[id] = ce;
}

// ---------------- scan2b: serial over NSUP supers ----------------
__global__ __launch_bounds__(256)
void scan2b_kernel(const float* __restrict__ SP, const float* __restrict__ SE,
                   float* __restrict__ Hsup)
{
  int id = blockIdx.x * 256 + threadIdx.x;  // BATCH*QDN = 6144
  int q = id % QDN;
  int b = id / QDN;
  float carry = 0.f;
#pragma unroll
  for (int s = 0; s < NSUP; ++s) {
    size_t idx = ((size_t)(b * NSUP + s)) * QDN + q;
    Hsup[idx] = carry;
    carry = fmaf(SP[idx], carry, SE[idx]);
  }
}

// ---------------- scan2c: expand to per-chunk inbound (bf16 out) ----------------
__global__ __launch_bounds__(256)
void scan2c_kernel(const unsigned* __restrict__ PE, const float* __restrict__ Hsup,
                   ushort* __restrict__ Hin)
{
  int id = blockIdx.x * 256 + threadIdx.x;  // 147456
  int q = id % QDN;
  int s = (id / QDN) % NSUP;
  int b = id / (QDN * NSUP);
  float h = Hsup[id];
#pragma unroll 6
  for (int c = 0; c < SUP; ++c) {
    size_t idx = ((size_t)(b * NCHUNK + s * SUP + c)) * QDN + q;
    Hin[idx] = f2bf(h);
    unsigned pe = PE[idx];
    float p = bf2f((ushort)(pe >> 16));
    float e = bf2f((ushort)(pe & 0xFFFF));
    h = fmaf(p, h, e);
  }
}

// ---------------- scan3: replay + y + gate -> bf16; LDS-staged B,C ----------------
__global__ __launch_bounds__(192)
void scan3_kernel(const ushort* __restrict__ dlt, const ushort* __restrict__ xmb,
                  const float* __restrict__ bc, const float* __restrict__ Alog,
                  const float* __restrict__ Dv, const ushort* __restrict__ xz1,
                  const ushort* __restrict__ Hin, ushort* __restrict__ yout)
{
  __shared__ float sBC[CHUNK][32];
  const int d = threadIdx.x;
  const int g = blockIdx.x % NCHUNK;
  const int b = blockIdx.x / NCHUNK;
  const int t0 = b * LSEQ + g * CHUNK;
  for (int i = threadIdx.x; i < CHUNK * 32; i += 192) {
    int l = i >> 5, j = i & 31;
    sBC[l][j] = bc[(size_t)(t0 + l) * 32 + j];
  }
  float Av[16];
#pragma unroll
  for (int j = 0; j < 16; ++j) Av[j] = -__expf(Alog[d * 16 + j]);
  const float Dd = Dv[d];
  float h[16];
  {
    size_t hb = ((size_t)(b * NCHUNK + g)) * QDN + d;
#pragma unroll
    for (int j = 0; j < 16; ++j) h[j] = bf2f(Hin[hb + j * 192]);
  }
  __syncthreads();
#pragma unroll 4
  for (int l = 0; l < CHUNK; ++l) {
    const int t = t0 + l;
    float dl = bf2f(dlt[(size_t)t * DI + d]);
    float u  = bf2f(xmb[(size_t)t * DI + d]);
    float z  = bf2f(xz1[(size_t)t * 384 + 192 + d]);
    float du = dl * u;
    float y0 = 0.f, y1 = 0.f, y2 = 0.f, y3 = 0.f;
#pragma unroll
    for (int j = 0; j < 16; ++j) {
      float a = __expf(dl * Av[j]);
      h[j] = fmaf(a, h[j], du * sBC[l][j]);
      float hc = h[j] * sBC[l][16 + j];
      if ((j & 3) == 0) y0 += hc;
      else if ((j & 3) == 1) y1 += hc;
      else if ((j & 3) == 2) y2 += hc;
      else y3 += hc;
    }
    float y = (y0 + y1) + (y2 + y3) + u * Dd;
    yout[(size_t)t * DI + d] = f2bf(y * silu_f(z));
  }
}

// ---------------- fused m_out_proj (silu gate) + out_proj (+residual) ----------------
__global__ __launch_bounds__(256)
void outproj_kernel(const ushort* __restrict__ yfin, const ushort* __restrict__ Wt2,
                    const ushort* __restrict__ xz0, const ushort* __restrict__ Wt3,
                    const float* __restrict__ x, float* __restrict__ out)
{
  __shared__ ushort yg_s[32][204];
  const int tid = threadIdx.x;
  const int wid = tid >> 6, lane = tid & 63;
  const int wm = wid >> 1, wn = wid & 1;
  const int l16 = lane & 15, quad = lane >> 4;
  const int m0 = blockIdx.x * 32;
  const f32x4 z4 = {0.f, 0.f, 0.f, 0.f};

  f32x4 acc[6];
#pragma unroll
  for (int j = 0; j < 6; ++j) acc[j] = z4;
  const int mt = m0 + wm * 16 + l16;
#pragma unroll
  for (int k0 = 0; k0 < 192; k0 += 32) {
    bf16x8 af = *(const bf16x8*)(yfin + (size_t)mt * 192 + k0 + quad * 8);
#pragma unroll
    for (int nj = 0; nj < 6; ++nj) {
      bf16x8 wf = *(const bf16x8*)(Wt2 + (size_t)(wn * 96 + nj * 16 + l16) * 192 + k0 + quad * 8);
      acc[nj] = __builtin_amdgcn_mfma_f32_16x16x32_bf16(wf, af, acc[nj], 0, 0, 0);
    }
  }
#pragma unroll
  for (int nj = 0; nj < 6; ++nj) {
    const int tok = wm * 16 + l16;
    const int nb = wn * 96 + nj * 16 + quad * 4;
    const ushort4 g4 = *(const ushort4*)(xz0 + (size_t)(m0 + tok) * 384 + 192 + nb);
    float v0 = acc[nj][0] * silu_f(bf2f(g4.x));
    float v1 = acc[nj][1] * silu_f(bf2f(g4.y));
    float v2 = acc[nj][2] * silu_f(bf2f(g4.z));
    float v3 = acc[nj][3] * silu_f(bf2f(g4.w));
    unsigned p0 = (unsigned)f2bf(v0) | ((unsigned)f2bf(v1) << 16);
    unsigned p1 = (unsigned)f2bf(v2) | ((unsigned)f2bf(v3) << 16);
    unsigned* dst = (unsigned*)&yg_s[tok][nb];
    dst[0] = p0; dst[1] = p1;
  }
  __syncthreads();

  f32x4 acc2[3];
#pragma unroll
  for (int j = 0; j < 3; ++j) acc2[j] = z4;
#pragma unroll
  for (int k0 = 0; k0 < 192; k0 += 32) {
    bf16x8 af = *(const bf16x8*)&yg_s[wm * 16 + l16][k0 + quad * 8];
#pragma unroll
    for (int nj = 0; nj < 3; ++nj) {
      bf16x8 wf = *(const bf16x8*)(Wt3 + (size_t)(wn * 48 + nj * 16 + l16) * 192 + k0 + quad * 8);
      acc2[nj] = __builtin_amdgcn_mfma_f32_16x16x32_bf16(wf, af, acc2[nj], 0, 0, 0);
    }
  }
#pragma unroll
  for (int nj = 0; nj < 3; ++nj) {
    const int tok = wm * 16 + l16;
    const int nb = wn * 48 + nj * 16 + quad * 4;
    const float4 r4 = *(const float4*)(x + (size_t)(m0 + tok) * 96 + nb);
    *(float4*)(out + (size_t)(m0 + tok) * 96 + nb) =
        make_float4(acc2[nj][0] + r4.x, acc2[nj][1] + r4.y,
                    acc2[nj][2] + r4.z, acc2[nj][3] + r4.w);
  }
}

// ---------------- launch ----------------
extern "C" void kernel_launch(void* const* d_in, const int* in_sizes, int n_in,
                              void* d_out, int out_size, void* d_ws, size_t ws_size,
                              hipStream_t stream)
{
  const float* x         = (const float*)d_in[0];
  const float* norm_w    = (const float*)d_in[1];
  const float* norm_b    = (const float*)d_in[2];
  const float* in_proj_w = (const float*)d_in[3];
  const float* conv2d_w  = (const float*)d_in[4];
  const float* m_in_proj = (const float*)d_in[5];
  const float* m_c1d_w   = (const float*)d_in[6];
  const float* m_c1d_b   = (const float*)d_in[7];
  const float* m_x_proj  = (const float*)d_in[8];
  const float* m_dt_w    = (const float*)d_in[9];
  const float* m_dt_b    = (const float*)d_in[10];
  const float* m_A_log   = (const float*)d_in[11];
  const float* m_D       = (const float*)d_in[12];
  const float* m_out_w   = (const float*)d_in[13];
  const float* out_w     = (const float*)d_in[14];
  float* out = (float*)d_out;

  char* wp = (char*)d_ws;
  auto alloc = [&](size_t bytes) {
    char* r = wp; wp += (bytes + 255) & ~(size_t)255; return r;
  };
  ushort* Wt0    = (ushort*)alloc(36864 * 2);      // [384][96]
  ushort* Wt1    = (ushort*)alloc(73728 * 2);      // [384][192]
  ushort* Wt2    = (ushort*)alloc(36864 * 2);      // [192][192]
  ushort* Wt3    = (ushort*)alloc(24576 * 2);      // [128][192]
  ushort* Wxt    = (ushort*)alloc(9216 * 2);       // [48][192]
  ushort* Wdtt   = (ushort*)alloc(6144 * 2);       // [192][32]
  float*  cw1T   = (float*)alloc(576 * 4);         // [3][192]
  ushort* xz0    = (ushort*)alloc((size_t)TT * 384 * 2);
  ushort* xc_bf  = (ushort*)alloc((size_t)TT * 192 * 2);
  ushort* xz1    = (ushort*)alloc((size_t)TT * 384 * 2);
  ushort* xmb_bf = (ushort*)alloc((size_t)TT * 192 * 2);
  float*  bc     = (float*)alloc((size_t)TT * 32 * 4);
  ushort* dlt    = (ushort*)alloc((size_t)TT * 192 * 2);
  unsigned* PE   = (unsigned*)alloc((size_t)BATCH * NCHUNK * QDN * 4);
  float*  SP     = (float*)alloc((size_t)BATCH * NSUP * QDN * 4);
  float*  SE     = (float*)alloc((size_t)BATCH * NSUP * QDN * 4);
  float*  Hsup   = (float*)alloc((size_t)BATCH * NSUP * QDN * 4);
  ushort* Hin    = (ushort*)alloc((size_t)BATCH * NCHUNK * QDN * 2);
  ushort* yfin   = (ushort*)alloc((size_t)TT * 192 * 2);

  castw_kernel<<<735, 256, 0, stream>>>(in_proj_w, m_in_proj, m_out_w, out_w,
                                        m_x_proj, m_dt_w, m_c1d_w,
                                        Wt0, Wt1, Wt2, Wt3, Wxt, Wdtt, cw1T);
  ln_inproj_kernel<<<dim3(TT / 128, 6), 256, 0, stream>>>(x, norm_w, norm_b, Wt0, xz0);
  conv2d_silu_kernel<<<TT * 48 / 256, 256, 0, stream>>>(xz0, conv2d_w, xc_bf);
  mfma_gemm_kernel<<<dim3(TT / 128, 6), 256, 0, stream>>>(xc_bf, 192, Wt1, 192, xz1, 384, 192);
  mprep_kernel<<<TT / 32, 256, 0, stream>>>(xz1, cw1T, m_c1d_b, Wxt, Wdtt, m_dt_b,
                                            m_A_log, xmb_bf, dlt, bc, PE);
  scan2a_kernel<<<BATCH * NSUP * QDN / 256, 256, 0, stream>>>(PE, SP, SE);
  scan2b_kernel<<<BATCH * QDN / 256, 256, 0, stream>>>(SP, SE, Hsup);
  scan2c_kernel<<<BATCH * NSUP * QDN / 256, 256, 0, stream>>>(PE, Hsup, Hin);
  scan3_kernel<<<BATCH * NCHUNK, 192, 0, stream>>>(dlt, xmb_bf, bc, m_A_log, m_D, xz1, Hin, yfin);
  outproj_kernel<<<TT / 32, 256, 0, stream>>>(yfin, Wt2, xz0, Wt3, x, out);
}